// Round 1
// baseline (3997.609 us; speedup 1.0000x reference)
//
#include <hip/hip_runtime.h>
#include <math.h>

// Problem constants
#define D_MODEL 512
#define NHEAD   8
#define DH      64
#define D_FF    2048
#define BATCH   16
#define SMAX    512
#define NTOK    (BATCH*SMAX)   // 8192
#define NLAYER  4

constexpr int MODE_EMBED = 0;  // C = A*B^T + bias + posenc(s,e)
constexpr int MODE_QKV   = 1;  // scatter into q/k/v [B,NH,S,DH], + bias
constexpr int MODE_RESID = 2;  // C = resid + A*B^T + bias
constexpr int MODE_RELU  = 3;  // C = relu(A*B^T + bias)

// ---------------------------------------------------------------------------
// Tiled fp32 GEMM: C[M x N] = op(A[M x K] * B[N x K]^T + bias)
// Tiles: BM=128, BN=64, BK=8. 256 threads, micro-tile 8x4 per thread.
// All dims used here are divisible by the tiles (M=8192; N in {512,1536,2048};
// K in {80,512,2048}) so no bounds checks.
// ---------------------------------------------------------------------------
template<int MODE>
__global__ __launch_bounds__(256)
void gemm_bt(const float* __restrict__ A, const float* __restrict__ Bm,
             const float* __restrict__ bias, const float* __restrict__ resid,
             float* __restrict__ C, float* __restrict__ qd,
             float* __restrict__ kd, float* __restrict__ vd,
             int K, int N)
{
  __shared__ float As[8][132];   // k-major, padded (bank-conflict free-ish)
  __shared__ float Bs[8][68];
  const int tid = threadIdx.x;
  const int m0 = blockIdx.y * 128;
  const int n0 = blockIdx.x * 64;
  const int tx = tid & 15, ty = tid >> 4;
  const int a_k = tid & 7, a_m = tid >> 3;   // a_m in 0..31

  float acc[8][4] = {};

  const float* Ag = A  + (long)(m0 + a_m) * K + a_k;
  const float* Bg = Bm + (long)(n0 + a_m) * K + a_k;

  for (int k0 = 0; k0 < K; k0 += 8) {
#pragma unroll
    for (int i = 0; i < 4; i++)
      As[a_k][a_m + 32*i] = Ag[k0 + (long)32*i*K];
#pragma unroll
    for (int i = 0; i < 2; i++)
      Bs[a_k][a_m + 32*i] = Bg[k0 + (long)32*i*K];
    __syncthreads();
#pragma unroll
    for (int kk = 0; kk < 8; kk++) {
      float a[8], bv[4];
#pragma unroll
      for (int r = 0; r < 8; r++) a[r] = As[kk][ty*8 + r];
#pragma unroll
      for (int c = 0; c < 4; c++) bv[c] = Bs[kk][tx*4 + c];
#pragma unroll
      for (int r = 0; r < 8; r++)
#pragma unroll
        for (int c = 0; c < 4; c++)
          acc[r][c] += a[r] * bv[c];
    }
    __syncthreads();
  }

  const int n_base = n0 + tx*4;
  if (MODE == MODE_QKV) {
    // BN=64 tile lies entirely inside one of {q,k,v} and one head region.
    const int which = n0 >> 9;          // 0:q 1:k 2:v
    const int head  = (n0 >> 6) & 7;
    float* dst = (which == 0) ? qd : (which == 1) ? kd : vd;
#pragma unroll
    for (int r = 0; r < 8; r++) {
      int m = m0 + ty*8 + r;
      int bb = m >> 9, s = m & 511;
      float4 v4;
      v4.x = acc[r][0] + bias[n_base+0];
      v4.y = acc[r][1] + bias[n_base+1];
      v4.z = acc[r][2] + bias[n_base+2];
      v4.w = acc[r][3] + bias[n_base+3];
      *(float4*)(dst + (long)((bb*8 + head)*512 + s)*64 + (n_base & 63)) = v4;
    }
  } else {
#pragma unroll
    for (int r = 0; r < 8; r++) {
      int m = m0 + ty*8 + r;
      float4 v4;
      float* vp = &v4.x;
#pragma unroll
      for (int c = 0; c < 4; c++) {
        int e = n_base + c;
        float v = acc[r][c] + bias[e];
        if (MODE == MODE_EMBED) {
          int s = m & 511;
          float dv  = __expf((float)(e & ~1) * (-9.210340371976184f / 512.0f));
          float ang = (float)s * dv;
          v += (e & 1) ? cosf(ang) : sinf(ang);
        }
        if (MODE == MODE_RESID) v += resid[(long)m*N + e];
        if (MODE == MODE_RELU)  v = fmaxf(v, 0.0f);
        vp[c] = v;
      }
      *(float4*)(C + (long)m*N + n_base) = v4;
    }
  }
}

// ---------------------------------------------------------------------------
// Flash-style attention, fp32. One block = (batch b, head h, 64-query tile).
// q/k/v in [B, NH, S, DH] layout. Writes ctx in [B, S, D] layout.
// Key tiles past len are skipped (their softmax weight is exactly 0).
// ---------------------------------------------------------------------------
__global__ __launch_bounds__(256)
void attn_kernel(const float* __restrict__ qb, const float* __restrict__ kb,
                 const float* __restrict__ vb, const int* __restrict__ lens,
                 float* __restrict__ ctx)
{
  __shared__ float Qt[64][72];    // Q^T: [d][q]
  __shared__ float KtPs[64][72];  // K^T: [d][k], then reused as P: [k][q]
  __shared__ float Vs[64][72];    // V:   [k][d]
  const int qt = blockIdx.x, hh = blockIdx.y, b = blockIdx.z;
  const int tid = threadIdx.x;
  const int tx = tid & 15, ty = tid >> 4;
  const int len = lens[b];
  const float* Qg = qb + (long)((b*8 + hh)*512 + qt*64) * 64;
  const float* Kg = kb + (long)((b*8 + hh)*512) * 64;
  const float* Vg = vb + (long)((b*8 + hh)*512) * 64;

#pragma unroll
  for (int i = 0; i < 4; i++) {
    int idx = tid + 256*i;
    int q = idx >> 4, d4 = (idx & 15) * 4;
    float4 t = *(const float4*)(Qg + q*64 + d4);
    Qt[d4+0][q] = t.x; Qt[d4+1][q] = t.y; Qt[d4+2][q] = t.z; Qt[d4+3][q] = t.w;
  }

  float o[4][4] = {};
  float mrow[4] = {-1e30f, -1e30f, -1e30f, -1e30f};
  float lrow[4] = {};
  const int ntiles = (len + 63) >> 6;   // len >= 256 so >= 4 tiles
  __syncthreads();

  for (int kt = 0; kt < ntiles; kt++) {
#pragma unroll
    for (int i = 0; i < 4; i++) {
      int idx = tid + 256*i;
      int kx = idx >> 4, d4 = (idx & 15) * 4;
      float4 t  = *(const float4*)(Kg + (long)(kt*64 + kx)*64 + d4);
      KtPs[d4+0][kx] = t.x; KtPs[d4+1][kx] = t.y;
      KtPs[d4+2][kx] = t.z; KtPs[d4+3][kx] = t.w;
      float4 tv = *(const float4*)(Vg + (long)(kt*64 + kx)*64 + d4);
      *(float4*)&Vs[kx][d4] = tv;
    }
    __syncthreads();

    float sc[4][4] = {};
#pragma unroll 8
    for (int kk = 0; kk < 64; kk++) {
      float4 aq = *(const float4*)&Qt[kk][ty*4];
      float4 ak = *(const float4*)&KtPs[kk][tx*4];
      const float* ap = &aq.x; const float* kp = &ak.x;
#pragma unroll
      for (int rq = 0; rq < 4; rq++)
#pragma unroll
        for (int rc = 0; rc < 4; rc++)
          sc[rq][rc] += ap[rq] * kp[rc];
    }
    __syncthreads();   // everyone done reading KtPs as K^T

    // scale + key mask
#pragma unroll
    for (int rq = 0; rq < 4; rq++)
#pragma unroll
      for (int rc = 0; rc < 4; rc++) {
        float s = sc[rq][rc] * 0.125f;    // 1/sqrt(64)
        int kglob = kt*64 + tx*4 + rc;
        sc[rq][rc] = (kglob < len) ? s : -1e30f;
      }

    float p[4][4];
#pragma unroll
    for (int rq = 0; rq < 4; rq++) {
      float tmax = fmaxf(fmaxf(sc[rq][0], sc[rq][1]), fmaxf(sc[rq][2], sc[rq][3]));
#pragma unroll
      for (int off = 1; off < 16; off <<= 1)
        tmax = fmaxf(tmax, __shfl_xor(tmax, off));
      float newm  = fmaxf(mrow[rq], tmax);
      float alpha = __expf(mrow[rq] - newm);
      float psum = 0.f;
#pragma unroll
      for (int rc = 0; rc < 4; rc++) { p[rq][rc] = __expf(sc[rq][rc] - newm); psum += p[rq][rc]; }
#pragma unroll
      for (int off = 1; off < 16; off <<= 1)
        psum += __shfl_xor(psum, off);
      lrow[rq] = lrow[rq] * alpha + psum;
      mrow[rq] = newm;
#pragma unroll
      for (int rd = 0; rd < 4; rd++) o[rq][rd] *= alpha;
    }

    // store P as [k][q] into KtPs
#pragma unroll
    for (int rc = 0; rc < 4; rc++)
#pragma unroll
      for (int rq = 0; rq < 4; rq++)
        KtPs[tx*4 + rc][ty*4 + rq] = p[rq][rc];
    __syncthreads();

#pragma unroll 8
    for (int kk = 0; kk < 64; kk++) {
      float4 ap4 = *(const float4*)&KtPs[kk][ty*4];
      float4 av4 = *(const float4*)&Vs[kk][tx*4];
      const float* pp = &ap4.x; const float* vp = &av4.x;
#pragma unroll
      for (int rq = 0; rq < 4; rq++)
#pragma unroll
        for (int rd = 0; rd < 4; rd++)
          o[rq][rd] += pp[rq] * vp[rd];
    }
    __syncthreads();
  }

#pragma unroll
  for (int rq = 0; rq < 4; rq++) {
    float inv = 1.0f / lrow[rq];
    int s = qt*64 + ty*4 + rq;
    float4 v4;
    v4.x = o[rq][0]*inv; v4.y = o[rq][1]*inv; v4.z = o[rq][2]*inv; v4.w = o[rq][3]*inv;
    *(float4*)(ctx + (long)(b*512 + s)*512 + hh*64 + tx*4) = v4;
  }
}

// ---------------------------------------------------------------------------
// LayerNorm over D=512. One block (128 threads, float4 each) per row.
// ---------------------------------------------------------------------------
__global__ __launch_bounds__(128)
void ln_kernel(const float* __restrict__ in, const float* __restrict__ g,
               const float* __restrict__ bb, float* __restrict__ out)
{
  const int row = blockIdx.x, tid = threadIdx.x;
  float4 x = ((const float4*)(in + (long)row*512))[tid];
  float s  = x.x + x.y + x.z + x.w;
  float s2 = x.x*x.x + x.y*x.y + x.z*x.z + x.w*x.w;
#pragma unroll
  for (int off = 1; off < 64; off <<= 1) {
    s  += __shfl_xor(s, off);
    s2 += __shfl_xor(s2, off);
  }
  __shared__ float rb[4];
  if ((tid & 63) == 0) { rb[(tid>>6)*2] = s; rb[(tid>>6)*2+1] = s2; }
  __syncthreads();
  s = rb[0] + rb[2]; s2 = rb[1] + rb[3];
  const float mean = s * (1.f/512.f);
  const float var  = fmaxf(s2 * (1.f/512.f) - mean*mean, 0.f);
  const float rstd = rsqrtf(var + 1e-5f);
  const int e = tid*4;
  float4 o;
  o.x = (x.x-mean)*rstd*g[e+0] + bb[e+0];
  o.y = (x.y-mean)*rstd*g[e+1] + bb[e+1];
  o.z = (x.z-mean)*rstd*g[e+2] + bb[e+2];
  o.w = (x.w-mean)*rstd*g[e+3] + bb[e+3];
  ((float4*)(out + (long)row*512))[tid] = o;
}

// ---------------------------------------------------------------------------
// Output init: pooled <- 0, lens (as float) at [8192..8207]
// ---------------------------------------------------------------------------
__global__ __launch_bounds__(256)
void out_init(float* __restrict__ out, const int* __restrict__ lens)
{
  int i = blockIdx.x*256 + threadIdx.x;
  if (i < 8192) out[i] = 0.f;
  else if (i < 8192 + 16) out[i] = (float)lens[i - 8192];
}

// ---------------------------------------------------------------------------
// Masked mean pool: out[b,d] += (1/len) * sum_{s in chunk, s<len} h[b,s,d]
// grid (8 s-chunks, 16 batches), 256 threads (2 dims each)
// ---------------------------------------------------------------------------
__global__ __launch_bounds__(256)
void pool_kernel(const float* __restrict__ h, const int* __restrict__ lens,
                 float* __restrict__ out)
{
  const int b = blockIdx.y;
  const int s0 = blockIdx.x * 64;
  const int len = lens[b];
  if (s0 >= len) return;
  const int send = min(s0 + 64, len);
  const int tid = threadIdx.x;
  float acc0 = 0.f, acc1 = 0.f;
  for (int s = s0; s < send; s++) {
    const float* row = h + (long)(b*512 + s)*512;
    acc0 += row[tid];
    acc1 += row[tid + 256];
  }
  const float inv = 1.0f / (float)len;
  atomicAdd(out + b*512 + tid,       acc0 * inv);
  atomicAdd(out + b*512 + tid + 256, acc1 * inv);
}

// ---------------------------------------------------------------------------
extern "C" void kernel_launch(void* const* d_in, const int* in_sizes, int n_in,
                              void* d_out, int out_size, void* d_ws, size_t ws_size,
                              hipStream_t stream)
{
  const float* x    = (const float*)d_in[0];
  const int*   lens = (const int*)  d_in[1];
  const float* We   = (const float*)d_in[2];
  const float* be   = (const float*)d_in[3];
  const float* Wqkv = (const float*)d_in[4];
  const float* bqkv = (const float*)d_in[5];
  const float* Wo   = (const float*)d_in[6];
  const float* bo   = (const float*)d_in[7];
  const float* ln1g = (const float*)d_in[8];
  const float* ln1b = (const float*)d_in[9];
  const float* W1   = (const float*)d_in[10];
  const float* b1   = (const float*)d_in[11];
  const float* W2   = (const float*)d_in[12];
  const float* b2   = (const float*)d_in[13];
  const float* ln2g = (const float*)d_in[14];
  const float* ln2b = (const float*)d_in[15];
  float* out = (float*)d_out;

  // Workspace layout (floats): 160 MiB total
  float* ws  = (float*)d_ws;
  const long TOK_D = (long)NTOK * D_MODEL;       // 4M floats
  float* h   = ws;
  float* q   = ws + 1*TOK_D;
  float* k   = ws + 2*TOK_D;
  float* v   = ws + 3*TOK_D;
  float* ctx = ws + 4*TOK_D;
  float* tmp = ws + 5*TOK_D;
  float* ff  = ws + 6*TOK_D;                     // 16M floats

  const dim3 blk(256);

  // 1) embedding + positional encoding: h = x*We^T + be + pe
  gemm_bt<MODE_EMBED><<<dim3(D_MODEL/64, NTOK/128), blk, 0, stream>>>(
      x, We, be, nullptr, h, nullptr, nullptr, nullptr, 80, D_MODEL);

  for (int l = 0; l < NLAYER; l++) {
    const float* Wqkv_l = Wqkv + (long)l * 3*D_MODEL * D_MODEL;
    const float* bqkv_l = bqkv + (long)l * 3*D_MODEL;
    const float* Wo_l   = Wo   + (long)l * D_MODEL * D_MODEL;
    const float* bo_l   = bo   + (long)l * D_MODEL;
    const float* W1_l   = W1   + (long)l * D_FF * D_MODEL;
    const float* b1_l   = b1   + (long)l * D_FF;
    const float* W2_l   = W2   + (long)l * D_MODEL * D_FF;
    const float* b2_l   = b2   + (long)l * D_MODEL;

    // 2a) qkv = h*Wqkv^T + bqkv, scattered to q/k/v [B,NH,S,DH]
    gemm_bt<MODE_QKV><<<dim3(3*D_MODEL/64, NTOK/128), blk, 0, stream>>>(
        h, Wqkv_l, bqkv_l, nullptr, nullptr, q, k, v, D_MODEL, 3*D_MODEL);

    // 2b) attention -> ctx [B,S,D]
    attn_kernel<<<dim3(SMAX/64, NHEAD, BATCH), blk, 0, stream>>>(q, k, v, lens, ctx);

    // 2c) tmp = h + ctx*Wo^T + bo
    gemm_bt<MODE_RESID><<<dim3(D_MODEL/64, NTOK/128), blk, 0, stream>>>(
        ctx, Wo_l, bo_l, h, tmp, nullptr, nullptr, nullptr, D_MODEL, D_MODEL);

    // 2d) h = LN(tmp; ln1)
    ln_kernel<<<dim3(NTOK), dim3(128), 0, stream>>>(tmp, ln1g + l*D_MODEL, ln1b + l*D_MODEL, h);

    // 2e) ff = relu(h*W1^T + b1)
    gemm_bt<MODE_RELU><<<dim3(D_FF/64, NTOK/128), blk, 0, stream>>>(
        h, W1_l, b1_l, nullptr, ff, nullptr, nullptr, nullptr, D_MODEL, D_FF);

    // 2f) tmp = h + ff*W2^T + b2
    gemm_bt<MODE_RESID><<<dim3(D_MODEL/64, NTOK/128), blk, 0, stream>>>(
        ff, W2_l, b2_l, h, tmp, nullptr, nullptr, nullptr, D_FF, D_MODEL);

    // 2g) h = LN(tmp; ln2)
    ln_kernel<<<dim3(NTOK), dim3(128), 0, stream>>>(tmp, ln2g + l*D_MODEL, ln2b + l*D_MODEL, h);
  }

  // 3) masked mean pool + lens output
  out_init<<<dim3((8192 + 16 + 255) / 256), blk, 0, stream>>>(out, lens);
  pool_kernel<<<dim3(SMAX/64, BATCH), blk, 0, stream>>>(h, lens, out);
}

// Round 2
// 1319.737 us; speedup vs baseline: 3.0291x; 3.0291x over previous
//
#include <hip/hip_runtime.h>
#include <math.h>

// Problem constants
#define D_MODEL 512
#define NHEAD   8
#define DH      64
#define D_FF    2048
#define BATCH   16
#define SMAX    512
#define NTOK    (BATCH*SMAX)   // 8192
#define NLAYER  4

constexpr int MODE_QKV   = 1;  // scatter into q/k/v [B,NH,S,DH], + bias (fp32)
constexpr int MODE_RESID = 2;  // Cf = resid + A*B^T + bias (fp32)
constexpr int MODE_RELU  = 3;  // Cb = bf16(relu(A*B^T + bias))

typedef __attribute__((ext_vector_type(8))) __bf16 bf16x8;
typedef __attribute__((ext_vector_type(4))) float  f32x4;

__device__ __forceinline__ unsigned short f2bf(float f) {
  union { float f; unsigned u; } v; v.f = f;
  unsigned r = v.u + 0x7FFFu + ((v.u >> 16) & 1u);   // RNE
  return (unsigned short)(r >> 16);
}

__device__ __forceinline__ void gl_lds16(const unsigned short* g, unsigned short* l) {
  __builtin_amdgcn_global_load_lds(
      (const __attribute__((address_space(1))) unsigned int*)g,
      (__attribute__((address_space(3)))       unsigned int*)l, 16, 0, 0);
}

// ---------------------------------------------------------------------------
// bf16 MFMA GEMM: C[M x N] = op(A[M x K] * B[N x K]^T + bias)
// 128x128 tile, BK=32, 256 threads = 4 waves (2x2), 4x4 16x16x32 frags/wave.
// m97-verified structure: global_load_lds width=16 staging, 2-barrier K-loop.
// A,B are bf16 (ushort bits); epilogue in fp32.
// ---------------------------------------------------------------------------
template<int MODE>
__global__ __launch_bounds__(256)
void gemm_mfma(const unsigned short* __restrict__ A,
               const unsigned short* __restrict__ Bw,
               const float* __restrict__ bias, const float* __restrict__ resid,
               float* __restrict__ Cf, unsigned short* __restrict__ Cb,
               float* __restrict__ qd, float* __restrict__ kd,
               float* __restrict__ vd, int K, int N)
{
  __shared__ unsigned short As[128*32];   // 8 KB, row-major [m][k], unpadded
  __shared__ unsigned short Bs[128*32];   // (global_load_lds needs linear order)
  const int tid  = threadIdx.x;
  const int m0   = blockIdx.y * 128, n0 = blockIdx.x * 128;
  const int lane = tid & 63;
  const int wm   = ((tid >> 6) & 1) * 64;  // wave m-offset
  const int wn   = (tid >> 7) * 64;        // wave n-offset
  const int l15  = lane & 15, quad = lane >> 4;

  f32x4 acc[4][4] = {};

  // staging: thread t loads 8 bf16 (16B) at linear tile element t*8
  const int sr = tid >> 2;           // tile row 0..63
  const int sk = (tid & 3) * 8;      // k offset 0..24
  const unsigned short* Ag = A  + (long)(m0 + sr) * K + sk;
  const unsigned short* Bg = Bw + (long)(n0 + sr) * K + sk;
  unsigned short* Ad0 = &As[tid * 8];
  unsigned short* Ad1 = &As[2048 + tid * 8];
  unsigned short* Bd0 = &Bs[tid * 8];
  unsigned short* Bd1 = &Bs[2048 + tid * 8];
  const long rowskip = (long)64 * K;

  for (int k0 = 0; k0 < K; k0 += 32) {
    __syncthreads();
    gl_lds16(Ag, Ad0);
    gl_lds16(Ag + rowskip, Ad1);
    gl_lds16(Bg, Bd0);
    gl_lds16(Bg + rowskip, Bd1);
    Ag += 32; Bg += 32;
    __syncthreads();   // compiler emits vmcnt(0) drain here

    bf16x8 af[4], bfv[4];
#pragma unroll
    for (int i = 0; i < 4; i++)
      af[i] = *(const bf16x8*)&As[(wm + i*16 + l15)*32 + quad*8];
#pragma unroll
    for (int j = 0; j < 4; j++)
      bfv[j] = *(const bf16x8*)&Bs[(wn + j*16 + l15)*32 + quad*8];
#pragma unroll
    for (int i = 0; i < 4; i++)
#pragma unroll
      for (int j = 0; j < 4; j++)
        acc[i][j] = __builtin_amdgcn_mfma_f32_16x16x32_bf16(af[i], bfv[j], acc[i][j], 0, 0, 0);
  }

  // epilogue: D[row = quad*4+r][col = l15] within each 16x16 tile (m89-verified)
#pragma unroll
  for (int i = 0; i < 4; i++) {
    const int mb = m0 + wm + i*16 + quad*4;
#pragma unroll
    for (int j = 0; j < 4; j++) {
      const int nn = n0 + wn + j*16 + l15;
      const float bv = bias[nn];
      if (MODE == MODE_QKV) {
        const int which = nn >> 9;
        const int head  = (nn >> 6) & 7;
        const int col   = nn & 63;
        float* dst = (which == 0) ? qd : (which == 1) ? kd : vd;
#pragma unroll
        for (int r = 0; r < 4; r++) {
          int m = mb + r; int bb = m >> 9, s = m & 511;
          dst[(long)((bb*8 + head)*512 + s)*64 + col] = acc[i][j][r] + bv;
        }
      } else if (MODE == MODE_RELU) {
#pragma unroll
        for (int r = 0; r < 4; r++) {
          int m = mb + r;
          Cb[(long)m*N + nn] = f2bf(fmaxf(acc[i][j][r] + bv, 0.f));
        }
      } else {  // MODE_RESID
#pragma unroll
        for (int r = 0; r < 4; r++) {
          int m = mb + r;
          Cf[(long)m*N + nn] = acc[i][j][r] + bv + resid[(long)m*N + nn];
        }
      }
    }
  }
}

// ---------------------------------------------------------------------------
// fp32 embedding GEMM (K=80): h = x*We^T + be + posenc; also writes bf16 copy.
// BM=128, BN=64, BK=8, 256 threads, 8x4 micro-tile.
// ---------------------------------------------------------------------------
__global__ __launch_bounds__(256)
void gemm_embed(const float* __restrict__ A, const float* __restrict__ Bm,
                const float* __restrict__ bias, float* __restrict__ C,
                unsigned short* __restrict__ Cb, int K, int N)
{
  __shared__ float As[8][132];
  __shared__ float Bs[8][68];
  const int tid = threadIdx.x;
  const int m0 = blockIdx.y * 128;
  const int n0 = blockIdx.x * 64;
  const int tx = tid & 15, ty = tid >> 4;
  const int a_k = tid & 7, a_m = tid >> 3;

  float acc[8][4] = {};
  const float* Ag = A  + (long)(m0 + a_m) * K + a_k;
  const float* Bg = Bm + (long)(n0 + a_m) * K + a_k;

  for (int k0 = 0; k0 < K; k0 += 8) {
#pragma unroll
    for (int i = 0; i < 4; i++)
      As[a_k][a_m + 32*i] = Ag[k0 + (long)32*i*K];
#pragma unroll
    for (int i = 0; i < 2; i++)
      Bs[a_k][a_m + 32*i] = Bg[k0 + (long)32*i*K];
    __syncthreads();
#pragma unroll
    for (int kk = 0; kk < 8; kk++) {
      float a[8], bv[4];
#pragma unroll
      for (int r = 0; r < 8; r++) a[r] = As[kk][ty*8 + r];
#pragma unroll
      for (int c = 0; c < 4; c++) bv[c] = Bs[kk][tx*4 + c];
#pragma unroll
      for (int r = 0; r < 8; r++)
#pragma unroll
        for (int c = 0; c < 4; c++)
          acc[r][c] += a[r] * bv[c];
    }
    __syncthreads();
  }

  const int n_base = n0 + tx*4;
#pragma unroll
  for (int r = 0; r < 8; r++) {
    int m = m0 + ty*8 + r;
    int s = m & 511;
    float4 v4; float* vp = &v4.x;
#pragma unroll
    for (int c = 0; c < 4; c++) {
      int e = n_base + c;
      float dv  = __expf((float)(e & ~1) * (-9.210340371976184f / 512.0f));
      float ang = (float)s * dv;
      vp[c] = acc[r][c] + bias[e] + ((e & 1) ? cosf(ang) : sinf(ang));
    }
    *(float4*)(C + (long)m*N + n_base) = v4;
    ushort4 ob;
    ob.x = f2bf(v4.x); ob.y = f2bf(v4.y); ob.z = f2bf(v4.z); ob.w = f2bf(v4.w);
    *(ushort4*)(Cb + (long)m*N + n_base) = ob;
  }
}

// ---------------------------------------------------------------------------
// Flash-style attention, fp32 compute, writes ctx as bf16 [B,S,D].
// ---------------------------------------------------------------------------
__global__ __launch_bounds__(256)
void attn_kernel(const float* __restrict__ qb, const float* __restrict__ kb,
                 const float* __restrict__ vb, const int* __restrict__ lens,
                 unsigned short* __restrict__ ctxb)
{
  __shared__ float Qt[64][72];    // Q^T: [d][q]
  __shared__ float KtPs[64][72];  // K^T: [d][k], then reused as P: [k][q]
  __shared__ float Vs[64][72];    // V:   [k][d]
  const int qt = blockIdx.x, hh = blockIdx.y, b = blockIdx.z;
  const int tid = threadIdx.x;
  const int tx = tid & 15, ty = tid >> 4;
  const int len = lens[b];
  const float* Qg = qb + (long)((b*8 + hh)*512 + qt*64) * 64;
  const float* Kg = kb + (long)((b*8 + hh)*512) * 64;
  const float* Vg = vb + (long)((b*8 + hh)*512) * 64;

#pragma unroll
  for (int i = 0; i < 4; i++) {
    int idx = tid + 256*i;
    int q = idx >> 4, d4 = (idx & 15) * 4;
    float4 t = *(const float4*)(Qg + q*64 + d4);
    Qt[d4+0][q] = t.x; Qt[d4+1][q] = t.y; Qt[d4+2][q] = t.z; Qt[d4+3][q] = t.w;
  }

  float o[4][4] = {};
  float mrow[4] = {-1e30f, -1e30f, -1e30f, -1e30f};
  float lrow[4] = {};
  const int ntiles = (len + 63) >> 6;
  __syncthreads();

  for (int kt = 0; kt < ntiles; kt++) {
#pragma unroll
    for (int i = 0; i < 4; i++) {
      int idx = tid + 256*i;
      int kx = idx >> 4, d4 = (idx & 15) * 4;
      float4 t  = *(const float4*)(Kg + (long)(kt*64 + kx)*64 + d4);
      KtPs[d4+0][kx] = t.x; KtPs[d4+1][kx] = t.y;
      KtPs[d4+2][kx] = t.z; KtPs[d4+3][kx] = t.w;
      float4 tv = *(const float4*)(Vg + (long)(kt*64 + kx)*64 + d4);
      *(float4*)&Vs[kx][d4] = tv;
    }
    __syncthreads();

    float sc[4][4] = {};
#pragma unroll 8
    for (int kk = 0; kk < 64; kk++) {
      float4 aq = *(const float4*)&Qt[kk][ty*4];
      float4 ak = *(const float4*)&KtPs[kk][tx*4];
      const float* ap = &aq.x; const float* kp = &ak.x;
#pragma unroll
      for (int rq = 0; rq < 4; rq++)
#pragma unroll
        for (int rc = 0; rc < 4; rc++)
          sc[rq][rc] += ap[rq] * kp[rc];
    }
    __syncthreads();

#pragma unroll
    for (int rq = 0; rq < 4; rq++)
#pragma unroll
      for (int rc = 0; rc < 4; rc++) {
        float s = sc[rq][rc] * 0.125f;
        int kglob = kt*64 + tx*4 + rc;
        sc[rq][rc] = (kglob < len) ? s : -1e30f;
      }

    float p[4][4];
#pragma unroll
    for (int rq = 0; rq < 4; rq++) {
      float tmax = fmaxf(fmaxf(sc[rq][0], sc[rq][1]), fmaxf(sc[rq][2], sc[rq][3]));
#pragma unroll
      for (int off = 1; off < 16; off <<= 1)
        tmax = fmaxf(tmax, __shfl_xor(tmax, off));
      float newm  = fmaxf(mrow[rq], tmax);
      float alpha = __expf(mrow[rq] - newm);
      float psum = 0.f;
#pragma unroll
      for (int rc = 0; rc < 4; rc++) { p[rq][rc] = __expf(sc[rq][rc] - newm); psum += p[rq][rc]; }
#pragma unroll
      for (int off = 1; off < 16; off <<= 1)
        psum += __shfl_xor(psum, off);
      lrow[rq] = lrow[rq] * alpha + psum;
      mrow[rq] = newm;
#pragma unroll
      for (int rd = 0; rd < 4; rd++) o[rq][rd] *= alpha;
    }

#pragma unroll
    for (int rc = 0; rc < 4; rc++)
#pragma unroll
      for (int rq = 0; rq < 4; rq++)
        KtPs[tx*4 + rc][ty*4 + rq] = p[rq][rc];
    __syncthreads();

#pragma unroll 8
    for (int kk = 0; kk < 64; kk++) {
      float4 ap4 = *(const float4*)&KtPs[kk][ty*4];
      float4 av4 = *(const float4*)&Vs[kk][tx*4];
      const float* pp = &ap4.x; const float* vp = &av4.x;
#pragma unroll
      for (int rq = 0; rq < 4; rq++)
#pragma unroll
        for (int rd = 0; rd < 4; rd++)
          o[rq][rd] += pp[rq] * vp[rd];
    }
    __syncthreads();
  }

#pragma unroll
  for (int rq = 0; rq < 4; rq++) {
    float inv = 1.0f / lrow[rq];
    int s = qt*64 + ty*4 + rq;
    ushort4 u4;
    u4.x = f2bf(o[rq][0]*inv); u4.y = f2bf(o[rq][1]*inv);
    u4.z = f2bf(o[rq][2]*inv); u4.w = f2bf(o[rq][3]*inv);
    *(ushort4*)(ctxb + (long)(b*512 + s)*512 + hh*64 + tx*4) = u4;
  }
}

// ---------------------------------------------------------------------------
// LayerNorm over D=512; writes fp32 out and bf16 copy.
// ---------------------------------------------------------------------------
__global__ __launch_bounds__(128)
void ln_kernel(const float* __restrict__ in, const float* __restrict__ g,
               const float* __restrict__ bb, float* __restrict__ out,
               unsigned short* __restrict__ outb)
{
  const int row = blockIdx.x, tid = threadIdx.x;
  float4 x = ((const float4*)(in + (long)row*512))[tid];
  float s  = x.x + x.y + x.z + x.w;
  float s2 = x.x*x.x + x.y*x.y + x.z*x.z + x.w*x.w;
#pragma unroll
  for (int off = 1; off < 64; off <<= 1) {
    s  += __shfl_xor(s, off);
    s2 += __shfl_xor(s2, off);
  }
  __shared__ float rb[4];
  if ((tid & 63) == 0) { rb[(tid>>6)*2] = s; rb[(tid>>6)*2+1] = s2; }
  __syncthreads();
  s = rb[0] + rb[2]; s2 = rb[1] + rb[3];
  const float mean = s * (1.f/512.f);
  const float var  = fmaxf(s2 * (1.f/512.f) - mean*mean, 0.f);
  const float rstd = rsqrtf(var + 1e-5f);
  const int e = tid*4;
  float4 o;
  o.x = (x.x-mean)*rstd*g[e+0] + bb[e+0];
  o.y = (x.y-mean)*rstd*g[e+1] + bb[e+1];
  o.z = (x.z-mean)*rstd*g[e+2] + bb[e+2];
  o.w = (x.w-mean)*rstd*g[e+3] + bb[e+3];
  ((float4*)(out + (long)row*512))[tid] = o;
  ushort4 ob;
  ob.x = f2bf(o.x); ob.y = f2bf(o.y); ob.z = f2bf(o.z); ob.w = f2bf(o.w);
  ((ushort4*)(outb + (long)row*512))[tid] = ob;
}

// fp32 -> bf16 cast (weights), float4 vectorized
__global__ __launch_bounds__(256)
void cvt_kernel(const float* __restrict__ in, unsigned short* __restrict__ out, int n4)
{
  int i = blockIdx.x*256 + threadIdx.x;
  if (i < n4) {
    float4 v = ((const float4*)in)[i];
    ushort4 o;
    o.x = f2bf(v.x); o.y = f2bf(v.y); o.z = f2bf(v.z); o.w = f2bf(v.w);
    ((ushort4*)out)[i] = o;
  }
}

__global__ __launch_bounds__(256)
void out_init(float* __restrict__ out, const int* __restrict__ lens)
{
  int i = blockIdx.x*256 + threadIdx.x;
  if (i < 8192) out[i] = 0.f;
  else if (i < 8192 + 16) out[i] = (float)lens[i - 8192];
}

__global__ __launch_bounds__(256)
void pool_kernel(const float* __restrict__ h, const int* __restrict__ lens,
                 float* __restrict__ out)
{
  const int b = blockIdx.y;
  const int s0 = blockIdx.x * 64;
  const int len = lens[b];
  if (s0 >= len) return;
  const int send = min(s0 + 64, len);
  const int tid = threadIdx.x;
  float acc0 = 0.f, acc1 = 0.f;
  for (int s = s0; s < send; s++) {
    const float* row = h + (long)(b*512 + s)*512;
    acc0 += row[tid];
    acc1 += row[tid + 256];
  }
  const float inv = 1.0f / (float)len;
  atomicAdd(out + b*512 + tid,       acc0 * inv);
  atomicAdd(out + b*512 + tid + 256, acc1 * inv);
}

// ---------------------------------------------------------------------------
extern "C" void kernel_launch(void* const* d_in, const int* in_sizes, int n_in,
                              void* d_out, int out_size, void* d_ws, size_t ws_size,
                              hipStream_t stream)
{
  const float* x    = (const float*)d_in[0];
  const int*   lens = (const int*)  d_in[1];
  const float* We   = (const float*)d_in[2];
  const float* be   = (const float*)d_in[3];
  const float* Wqkv = (const float*)d_in[4];
  const float* bqkv = (const float*)d_in[5];
  const float* Wo   = (const float*)d_in[6];
  const float* bo   = (const float*)d_in[7];
  const float* ln1g = (const float*)d_in[8];
  const float* ln1b = (const float*)d_in[9];
  const float* W1   = (const float*)d_in[10];
  const float* b1   = (const float*)d_in[11];
  const float* W2   = (const float*)d_in[12];
  const float* b2   = (const float*)d_in[13];
  const float* ln2g = (const float*)d_in[14];
  const float* ln2b = (const float*)d_in[15];
  float* out = (float*)d_out;

  // Workspace layout
  const long TOK_D = (long)NTOK * D_MODEL;              // 4M elements
  float* ws  = (float*)d_ws;
  float* h   = ws;                                      // fp32 [8192,512]
  float* tmp = ws + 1*TOK_D;
  float* q   = ws + 2*TOK_D;                            // [B,NH,S,DH]
  float* k   = ws + 3*TOK_D;
  float* v   = ws + 4*TOK_D;
  unsigned short* us    = (unsigned short*)(ws + 5*TOK_D);
  unsigned short* h_b   = us;                           // bf16 [8192,512]
  unsigned short* ctx_b = us + 1*TOK_D;
  unsigned short* ff_b  = us + 2*TOK_D;                 // bf16 [8192,2048]
  unsigned short* wq_b  = us + 6*TOK_D;                 // 4*1536*512
  unsigned short* wo_b  = wq_b + (long)NLAYER*3*D_MODEL*D_MODEL;
  unsigned short* w1_b  = wo_b + (long)NLAYER*D_MODEL*D_MODEL;
  unsigned short* w2_b  = w1_b + (long)NLAYER*D_FF*D_MODEL;

  const dim3 blk(256);

  // 0) weight casts fp32->bf16 (per launch; ~12.6M elems)
  {
    int n4;
    n4 = NLAYER*3*D_MODEL*D_MODEL/4;
    cvt_kernel<<<dim3((n4+255)/256), blk, 0, stream>>>(Wqkv, wq_b, n4);
    n4 = NLAYER*D_MODEL*D_MODEL/4;
    cvt_kernel<<<dim3((n4+255)/256), blk, 0, stream>>>(Wo, wo_b, n4);
    n4 = NLAYER*D_FF*D_MODEL/4;
    cvt_kernel<<<dim3((n4+255)/256), blk, 0, stream>>>(W1, w1_b, n4);
    n4 = NLAYER*D_MODEL*D_FF/4;
    cvt_kernel<<<dim3((n4+255)/256), blk, 0, stream>>>(W2, w2_b, n4);
  }

  // 1) embedding + posenc (fp32), writes h + h_b
  gemm_embed<<<dim3(D_MODEL/64, NTOK/128), blk, 0, stream>>>(
      x, We, be, h, h_b, 80, D_MODEL);

  for (int l = 0; l < NLAYER; l++) {
    const unsigned short* wq_l = wq_b + (long)l * 3*D_MODEL * D_MODEL;
    const unsigned short* wo_l = wo_b + (long)l * D_MODEL * D_MODEL;
    const unsigned short* w1_l = w1_b + (long)l * D_FF * D_MODEL;
    const unsigned short* w2_l = w2_b + (long)l * D_MODEL * D_FF;
    const float* bqkv_l = bqkv + (long)l * 3*D_MODEL;
    const float* bo_l   = bo   + (long)l * D_MODEL;
    const float* b1_l   = b1   + (long)l * D_FF;
    const float* b2_l   = b2   + (long)l * D_MODEL;

    // qkv = h*Wqkv^T + bqkv  -> q/k/v [B,NH,S,DH] fp32
    gemm_mfma<MODE_QKV><<<dim3(3*D_MODEL/128, NTOK/128), blk, 0, stream>>>(
        h_b, wq_l, bqkv_l, nullptr, nullptr, nullptr, q, k, v, D_MODEL, 3*D_MODEL);

    // attention -> ctx_b (bf16)
    attn_kernel<<<dim3(SMAX/64, NHEAD, BATCH), blk, 0, stream>>>(q, k, v, lens, ctx_b);

    // tmp = h + ctx*Wo^T + bo
    gemm_mfma<MODE_RESID><<<dim3(D_MODEL/128, NTOK/128), blk, 0, stream>>>(
        ctx_b, wo_l, bo_l, h, tmp, nullptr, nullptr, nullptr, nullptr, D_MODEL, D_MODEL);

    // h = LN(tmp; ln1) (+ bf16 copy)
    ln_kernel<<<dim3(NTOK), dim3(128), 0, stream>>>(
        tmp, ln1g + l*D_MODEL, ln1b + l*D_MODEL, h, h_b);

    // ff_b = bf16(relu(h*W1^T + b1))
    gemm_mfma<MODE_RELU><<<dim3(D_FF/128, NTOK/128), blk, 0, stream>>>(
        h_b, w1_l, b1_l, nullptr, nullptr, ff_b, nullptr, nullptr, nullptr, D_MODEL, D_FF);

    // tmp = h + ff*W2^T + b2
    gemm_mfma<MODE_RESID><<<dim3(D_MODEL/128, NTOK/128), blk, 0, stream>>>(
        ff_b, w2_l, b2_l, h, tmp, nullptr, nullptr, nullptr, nullptr, D_FF, D_MODEL);

    // h = LN(tmp; ln2) (+ bf16 copy)
    ln_kernel<<<dim3(NTOK), dim3(128), 0, stream>>>(
        tmp, ln2g + l*D_MODEL, ln2b + l*D_MODEL, h, h_b);
  }

  // 3) masked mean pool + lens output
  out_init<<<dim3((8192 + 16 + 255) / 256), blk, 0, stream>>>(out, lens);
  pool_kernel<<<dim3(SMAX/64, BATCH), blk, 0, stream>>>(h, lens, out);
}

// Round 3
// 864.116 us; speedup vs baseline: 4.6262x; 1.5273x over previous
//
#include <hip/hip_runtime.h>
#include <math.h>

// Problem constants
#define D_MODEL 512
#define NHEAD   8
#define DH      64
#define D_FF    2048
#define BATCH   16
#define SMAX    512
#define NTOK    (BATCH*SMAX)   // 8192
#define NLAYER  4

constexpr int MODE_QKV   = 1;  // scatter bf16 into q/kh/vt layouts, + bias
constexpr int MODE_RESID = 2;  // Cf = resid + A*B^T + bias (fp32)
constexpr int MODE_RELU  = 3;  // Cb = bf16(relu(A*B^T + bias))

typedef __attribute__((ext_vector_type(8))) __bf16 bf16x8;
typedef __attribute__((ext_vector_type(4))) float  f32x4;

__device__ __forceinline__ unsigned short f2bf(float f) {
  union { float f; unsigned u; } v; v.f = f;
  unsigned r = v.u + 0x7FFFu + ((v.u >> 16) & 1u);   // RNE
  return (unsigned short)(r >> 16);
}

__device__ __forceinline__ void gl_lds16(const unsigned short* g, unsigned short* l) {
  __builtin_amdgcn_global_load_lds(
      (const __attribute__((address_space(1))) unsigned int*)g,
      (__attribute__((address_space(3)))       unsigned int*)l, 16, 0, 0);
}

// ---------------------------------------------------------------------------
// bf16 MFMA GEMM: C[M x N] = op(A[M x K] * B[N x K]^T + bias)
// 128x128 tile, BK=32, 256 threads = 4 waves (2x2), 4x4 16x16x32 frags/wave.
// ---------------------------------------------------------------------------
template<int MODE>
__global__ __launch_bounds__(256)
void gemm_mfma(const unsigned short* __restrict__ A,
               const unsigned short* __restrict__ Bw,
               const float* __restrict__ bias, const float* __restrict__ resid,
               float* __restrict__ Cf, unsigned short* __restrict__ Cb,
               unsigned short* __restrict__ qd, unsigned short* __restrict__ kd,
               unsigned short* __restrict__ vd, int K, int N)
{
  __shared__ __attribute__((aligned(16))) unsigned short As[128*32];
  __shared__ __attribute__((aligned(16))) unsigned short Bs[128*32];
  const int tid  = threadIdx.x;
  const int m0   = blockIdx.y * 128, n0 = blockIdx.x * 128;
  const int lane = tid & 63;
  const int wm   = ((tid >> 6) & 1) * 64;
  const int wn   = (tid >> 7) * 64;
  const int l15  = lane & 15, quad = lane >> 4;

  f32x4 acc[4][4] = {};

  const int sr = tid >> 2;
  const int sk = (tid & 3) * 8;
  const unsigned short* Ag = A  + (long)(m0 + sr) * K + sk;
  const unsigned short* Bg = Bw + (long)(n0 + sr) * K + sk;
  unsigned short* Ad0 = &As[tid * 8];
  unsigned short* Ad1 = &As[2048 + tid * 8];
  unsigned short* Bd0 = &Bs[tid * 8];
  unsigned short* Bd1 = &Bs[2048 + tid * 8];
  const long rowskip = (long)64 * K;

  for (int k0 = 0; k0 < K; k0 += 32) {
    __syncthreads();
    gl_lds16(Ag, Ad0);
    gl_lds16(Ag + rowskip, Ad1);
    gl_lds16(Bg, Bd0);
    gl_lds16(Bg + rowskip, Bd1);
    Ag += 32; Bg += 32;
    __syncthreads();

    bf16x8 af[4], bfv[4];
#pragma unroll
    for (int i = 0; i < 4; i++)
      af[i] = *(const bf16x8*)&As[(wm + i*16 + l15)*32 + quad*8];
#pragma unroll
    for (int j = 0; j < 4; j++)
      bfv[j] = *(const bf16x8*)&Bs[(wn + j*16 + l15)*32 + quad*8];
#pragma unroll
    for (int i = 0; i < 4; i++)
#pragma unroll
      for (int j = 0; j < 4; j++)
        acc[i][j] = __builtin_amdgcn_mfma_f32_16x16x32_bf16(af[i], bfv[j], acc[i][j], 0, 0, 0);
  }

  // epilogue: D[row = quad*4+r][col = l15] per 16x16 tile
#pragma unroll
  for (int i = 0; i < 4; i++) {
    const int mb = m0 + wm + i*16 + quad*4;
#pragma unroll
    for (int j = 0; j < 4; j++) {
      const int nn = n0 + wn + j*16 + l15;
      const float bv = bias[nn];
      if (MODE == MODE_QKV) {
        const int which = nn >> 9;
        const int head  = (nn >> 6) & 7;
        const int col   = nn & 63;
#pragma unroll
        for (int r = 0; r < 4; r++) {
          int m = mb + r; int bb = m >> 9, s = m & 511;
          int bh = bb*8 + head;
          unsigned short o = f2bf(acc[i][j][r] + bv);
          if (which == 0)
            qd[((long)(bh*512 + s))*64 + col] = o;
          else if (which == 1)
            kd[(long)(bh*8 + (s>>6))*4096 + (col>>5)*2048 + (s&63)*32 + (col&31)] = o;
          else
            vd[(long)(bh*8 + (s>>6))*4096 + ((s&63)>>5)*2048 + col*32 + (s&31)] = o;
        }
      } else if (MODE == MODE_RELU) {
#pragma unroll
        for (int r = 0; r < 4; r++) {
          int m = mb + r;
          Cb[(long)m*N + nn] = f2bf(fmaxf(acc[i][j][r] + bv, 0.f));
        }
      } else {  // MODE_RESID
#pragma unroll
        for (int r = 0; r < 4; r++) {
          int m = mb + r;
          Cf[(long)m*N + nn] = acc[i][j][r] + bv + resid[(long)m*N + nn];
        }
      }
    }
  }
}

// ---------------------------------------------------------------------------
// MFMA flash attention. Block = (64-q tile, head, batch), 4 waves x 16 q-rows.
// q: bf16 [bh][s][64]; k: bf16 [bh][ktile][dh-half][row64][32];
// v^T: bf16 [bh][ktile][key-half][d64][32key]. Writes ctx bf16 [B,S,512].
// ---------------------------------------------------------------------------
__global__ __launch_bounds__(256)
void attn_mfma(const unsigned short* __restrict__ qg,
               const unsigned short* __restrict__ kh,
               const unsigned short* __restrict__ vth,
               const int* __restrict__ lens,
               unsigned short* __restrict__ ctxb)
{
  __shared__ __attribute__((aligned(16))) unsigned short Ks[2*64*32];
  __shared__ __attribute__((aligned(16))) unsigned short Vts[2*64*32];
  __shared__ __attribute__((aligned(16))) unsigned short Ps[4*16*72];
  const int qt = blockIdx.x, hh = blockIdx.y, b = blockIdx.z;
  const int bh = b*8 + hh;
  const int tid = threadIdx.x;
  const int w = tid >> 6, lane = tid & 63, l15 = lane & 15, quad = lane >> 4;
  const int len = lens[b];

  // Q fragments (held for whole kernel): rows qt*64 + w*16 + l15
  const unsigned short* qrow = qg + ((long)(bh*512 + qt*64 + w*16 + l15))*64;
  const bf16x8 qf0 = *(const bf16x8*)(qrow + quad*8);
  const bf16x8 qf1 = *(const bf16x8*)(qrow + 32 + quad*8);

  f32x4 O[4] = {};
  float mrow[4] = {-1e30f,-1e30f,-1e30f,-1e30f};
  float lrow[4] = {0.f,0.f,0.f,0.f};
  unsigned short* Pw = &Ps[w*16*72];
  const int ntiles = (len + 63) >> 6;

  for (int kt = 0; kt < ntiles; kt++) {
    __syncthreads();
    const unsigned short* Kg = kh  + ((long)(bh*8 + kt))*4096 + tid*8;
    const unsigned short* Vg = vth + ((long)(bh*8 + kt))*4096 + tid*8;
    gl_lds16(Kg,        &Ks[tid*8]);
    gl_lds16(Kg + 2048, &Ks[2048 + tid*8]);
    gl_lds16(Vg,        &Vts[tid*8]);
    gl_lds16(Vg + 2048, &Vts[2048 + tid*8]);
    __syncthreads();

    // S = Q K^T : per wave 16q x 64k, C-layout (row=q=quad*4+r, col=k=l15)
    f32x4 sc[4];
#pragma unroll
    for (int ks = 0; ks < 4; ks++) {
      bf16x8 kf0 = *(const bf16x8*)&Ks[       (ks*16 + l15)*32 + quad*8];
      bf16x8 kf1 = *(const bf16x8*)&Ks[2048 + (ks*16 + l15)*32 + quad*8];
      f32x4 z = {};
      z = __builtin_amdgcn_mfma_f32_16x16x32_bf16(qf0, kf0, z, 0, 0, 0);
      sc[ks] = __builtin_amdgcn_mfma_f32_16x16x32_bf16(qf1, kf1, z, 0, 0, 0);
    }

    // scale + key mask
#pragma unroll
    for (int ks = 0; ks < 4; ks++) {
      const bool valid = (kt*64 + ks*16 + l15) < len;
#pragma unroll
      for (int r = 0; r < 4; r++)
        sc[ks][r] = valid ? sc[ks][r]*0.125f : -1e30f;
    }

    // online softmax (row reduce over l15 bits only)
    float pv[4][4];
#pragma unroll
    for (int r = 0; r < 4; r++) {
      float mx = fmaxf(fmaxf(sc[0][r], sc[1][r]), fmaxf(sc[2][r], sc[3][r]));
      mx = fmaxf(mx, __shfl_xor(mx, 1));
      mx = fmaxf(mx, __shfl_xor(mx, 2));
      mx = fmaxf(mx, __shfl_xor(mx, 4));
      mx = fmaxf(mx, __shfl_xor(mx, 8));
      const float newm  = fmaxf(mrow[r], mx);
      const float alpha = __expf(mrow[r] - newm);
      float ps = 0.f;
#pragma unroll
      for (int ks = 0; ks < 4; ks++) { pv[ks][r] = __expf(sc[ks][r] - newm); ps += pv[ks][r]; }
      ps += __shfl_xor(ps, 1); ps += __shfl_xor(ps, 2);
      ps += __shfl_xor(ps, 4); ps += __shfl_xor(ps, 8);
      lrow[r] = lrow[r]*alpha + ps;
      mrow[r] = newm;
#pragma unroll
      for (int d = 0; d < 4; d++) O[d][r] *= alpha;
    }

    // P: C-layout -> A-layout via wave-private LDS (pad 72 breaks bank alias)
#pragma unroll
    for (int ks = 0; ks < 4; ks++)
#pragma unroll
      for (int r = 0; r < 4; r++)
        Pw[(quad*4 + r)*72 + ks*16 + l15] = f2bf(pv[ks][r]);
    asm volatile("s_waitcnt lgkmcnt(0)" ::: "memory");

    const bf16x8 pa0 = *(const bf16x8*)&Pw[l15*72 + quad*8];
    const bf16x8 pa1 = *(const bf16x8*)&Pw[l15*72 + 32 + quad*8];
#pragma unroll
    for (int d = 0; d < 4; d++) {
      bf16x8 vf0 = *(const bf16x8*)&Vts[       (d*16 + l15)*32 + quad*8];
      bf16x8 vf1 = *(const bf16x8*)&Vts[2048 + (d*16 + l15)*32 + quad*8];
      O[d] = __builtin_amdgcn_mfma_f32_16x16x32_bf16(pa0, vf0, O[d], 0, 0, 0);
      O[d] = __builtin_amdgcn_mfma_f32_16x16x32_bf16(pa1, vf1, O[d], 0, 0, 0);
    }
  }

  // write ctx (bf16 [B,S,512])
#pragma unroll
  for (int r = 0; r < 4; r++) {
    const float inv = 1.f / lrow[r];
    const long row = (long)(b*512 + qt*64 + w*16 + quad*4 + r)*512 + hh*64;
#pragma unroll
    for (int d = 0; d < 4; d++)
      ctxb[row + d*16 + l15] = f2bf(O[d][r] * inv);
  }
}

// ---------------------------------------------------------------------------
// fp32 embedding GEMM (K=80): h = x*We^T + be + posenc; writes fp32 + bf16.
// ---------------------------------------------------------------------------
__global__ __launch_bounds__(256)
void gemm_embed(const float* __restrict__ A, const float* __restrict__ Bm,
                const float* __restrict__ bias, float* __restrict__ C,
                unsigned short* __restrict__ Cb, int K, int N)
{
  __shared__ float As[8][132];
  __shared__ float Bs[8][68];
  const int tid = threadIdx.x;
  const int m0 = blockIdx.y * 128;
  const int n0 = blockIdx.x * 64;
  const int tx = tid & 15, ty = tid >> 4;
  const int a_k = tid & 7, a_m = tid >> 3;

  float acc[8][4] = {};
  const float* Ag = A  + (long)(m0 + a_m) * K + a_k;
  const float* Bg = Bm + (long)(n0 + a_m) * K + a_k;

  for (int k0 = 0; k0 < K; k0 += 8) {
#pragma unroll
    for (int i = 0; i < 4; i++)
      As[a_k][a_m + 32*i] = Ag[k0 + (long)32*i*K];
#pragma unroll
    for (int i = 0; i < 2; i++)
      Bs[a_k][a_m + 32*i] = Bg[k0 + (long)32*i*K];
    __syncthreads();
#pragma unroll
    for (int kk = 0; kk < 8; kk++) {
      float a[8], bv[4];
#pragma unroll
      for (int r = 0; r < 8; r++) a[r] = As[kk][ty*8 + r];
#pragma unroll
      for (int c = 0; c < 4; c++) bv[c] = Bs[kk][tx*4 + c];
#pragma unroll
      for (int r = 0; r < 8; r++)
#pragma unroll
        for (int c = 0; c < 4; c++)
          acc[r][c] += a[r] * bv[c];
    }
    __syncthreads();
  }

  const int n_base = n0 + tx*4;
#pragma unroll
  for (int r = 0; r < 8; r++) {
    int m = m0 + ty*8 + r;
    int s = m & 511;
    float4 v4; float* vp = &v4.x;
#pragma unroll
    for (int c = 0; c < 4; c++) {
      int e = n_base + c;
      float dv  = __expf((float)(e & ~1) * (-9.210340371976184f / 512.0f));
      float ang = (float)s * dv;
      vp[c] = acc[r][c] + bias[e] + ((e & 1) ? cosf(ang) : sinf(ang));
    }
    *(float4*)(C + (long)m*N + n_base) = v4;
    ushort4 ob;
    ob.x = f2bf(v4.x); ob.y = f2bf(v4.y); ob.z = f2bf(v4.z); ob.w = f2bf(v4.w);
    *(ushort4*)(Cb + (long)m*N + n_base) = ob;
  }
}

// ---------------------------------------------------------------------------
// LayerNorm over D=512; writes fp32 out and bf16 copy.
// ---------------------------------------------------------------------------
__global__ __launch_bounds__(128)
void ln_kernel(const float* __restrict__ in, const float* __restrict__ g,
               const float* __restrict__ bb, float* __restrict__ out,
               unsigned short* __restrict__ outb)
{
  const int row = blockIdx.x, tid = threadIdx.x;
  float4 x = ((const float4*)(in + (long)row*512))[tid];
  float s  = x.x + x.y + x.z + x.w;
  float s2 = x.x*x.x + x.y*x.y + x.z*x.z + x.w*x.w;
#pragma unroll
  for (int off = 1; off < 64; off <<= 1) {
    s  += __shfl_xor(s, off);
    s2 += __shfl_xor(s2, off);
  }
  __shared__ float rb[4];
  if ((tid & 63) == 0) { rb[(tid>>6)*2] = s; rb[(tid>>6)*2+1] = s2; }
  __syncthreads();
  s = rb[0] + rb[2]; s2 = rb[1] + rb[3];
  const float mean = s * (1.f/512.f);
  const float var  = fmaxf(s2 * (1.f/512.f) - mean*mean, 0.f);
  const float rstd = rsqrtf(var + 1e-5f);
  const int e = tid*4;
  float4 o;
  o.x = (x.x-mean)*rstd*g[e+0] + bb[e+0];
  o.y = (x.y-mean)*rstd*g[e+1] + bb[e+1];
  o.z = (x.z-mean)*rstd*g[e+2] + bb[e+2];
  o.w = (x.w-mean)*rstd*g[e+3] + bb[e+3];
  ((float4*)(out + (long)row*512))[tid] = o;
  ushort4 ob;
  ob.x = f2bf(o.x); ob.y = f2bf(o.y); ob.z = f2bf(o.z); ob.w = f2bf(o.w);
  ((ushort4*)(outb + (long)row*512))[tid] = ob;
}

// fp32 -> bf16 cast (weights)
__global__ __launch_bounds__(256)
void cvt_kernel(const float* __restrict__ in, unsigned short* __restrict__ out, int n4)
{
  int i = blockIdx.x*256 + threadIdx.x;
  if (i < n4) {
    float4 v = ((const float4*)in)[i];
    ushort4 o;
    o.x = f2bf(v.x); o.y = f2bf(v.y); o.z = f2bf(v.z); o.w = f2bf(v.w);
    ((ushort4*)out)[i] = o;
  }
}

__global__ __launch_bounds__(256)
void out_init(float* __restrict__ out, const int* __restrict__ lens)
{
  int i = blockIdx.x*256 + threadIdx.x;
  if (i < 8192) out[i] = 0.f;
  else if (i < 8192 + 16) out[i] = (float)lens[i - 8192];
}

__global__ __launch_bounds__(256)
void pool_kernel(const float* __restrict__ h, const int* __restrict__ lens,
                 float* __restrict__ out)
{
  const int b = blockIdx.y;
  const int s0 = blockIdx.x * 64;
  const int len = lens[b];
  if (s0 >= len) return;
  const int send = min(s0 + 64, len);
  const int tid = threadIdx.x;
  float acc0 = 0.f, acc1 = 0.f;
  for (int s = s0; s < send; s++) {
    const float* row = h + (long)(b*512 + s)*512;
    acc0 += row[tid];
    acc1 += row[tid + 256];
  }
  const float inv = 1.0f / (float)len;
  atomicAdd(out + b*512 + tid,       acc0 * inv);
  atomicAdd(out + b*512 + tid + 256, acc1 * inv);
}

// ---------------------------------------------------------------------------
extern "C" void kernel_launch(void* const* d_in, const int* in_sizes, int n_in,
                              void* d_out, int out_size, void* d_ws, size_t ws_size,
                              hipStream_t stream)
{
  const float* x    = (const float*)d_in[0];
  const int*   lens = (const int*)  d_in[1];
  const float* We   = (const float*)d_in[2];
  const float* be   = (const float*)d_in[3];
  const float* Wqkv = (const float*)d_in[4];
  const float* bqkv = (const float*)d_in[5];
  const float* Wo   = (const float*)d_in[6];
  const float* bo   = (const float*)d_in[7];
  const float* ln1g = (const float*)d_in[8];
  const float* ln1b = (const float*)d_in[9];
  const float* W1   = (const float*)d_in[10];
  const float* b1   = (const float*)d_in[11];
  const float* W2   = (const float*)d_in[12];
  const float* b2   = (const float*)d_in[13];
  const float* ln2g = (const float*)d_in[14];
  const float* ln2b = (const float*)d_in[15];
  float* out = (float*)d_out;

  // Workspace layout
  const long TOK_D = (long)NTOK * D_MODEL;              // 4,194,304
  float* ws  = (float*)d_ws;
  float* h   = ws;                                      // fp32 [8192,512]
  float* tmp = ws + 1*TOK_D;
  unsigned short* us    = (unsigned short*)(ws + 2*TOK_D);
  unsigned short* h_b   = us;                           // bf16 [8192,512]
  unsigned short* ctx_b = us + 1*TOK_D;
  unsigned short* q_b   = us + 2*TOK_D;                 // [bh][s][64]
  unsigned short* kh_b  = us + 3*TOK_D;                 // [bh][kt][half][64][32]
  unsigned short* vth_b = us + 4*TOK_D;                 // [bh][kt][half][64][32]
  unsigned short* ff_b  = us + 5*TOK_D;                 // bf16 [8192,2048]
  unsigned short* wq_b  = us + 9*TOK_D;
  unsigned short* wo_b  = wq_b + (long)NLAYER*3*D_MODEL*D_MODEL;
  unsigned short* w1_b  = wo_b + (long)NLAYER*D_MODEL*D_MODEL;
  unsigned short* w2_b  = w1_b + (long)NLAYER*D_FF*D_MODEL;

  const dim3 blk(256);

  // 0) weight casts fp32->bf16
  {
    int n4;
    n4 = NLAYER*3*D_MODEL*D_MODEL/4;
    cvt_kernel<<<dim3((n4+255)/256), blk, 0, stream>>>(Wqkv, wq_b, n4);
    n4 = NLAYER*D_MODEL*D_MODEL/4;
    cvt_kernel<<<dim3((n4+255)/256), blk, 0, stream>>>(Wo, wo_b, n4);
    n4 = NLAYER*D_FF*D_MODEL/4;
    cvt_kernel<<<dim3((n4+255)/256), blk, 0, stream>>>(W1, w1_b, n4);
    n4 = NLAYER*D_MODEL*D_FF/4;
    cvt_kernel<<<dim3((n4+255)/256), blk, 0, stream>>>(W2, w2_b, n4);
  }

  // 1) embedding + posenc (fp32), writes h + h_b
  gemm_embed<<<dim3(D_MODEL/64, NTOK/128), blk, 0, stream>>>(
      x, We, be, h, h_b, 80, D_MODEL);

  for (int l = 0; l < NLAYER; l++) {
    const unsigned short* wq_l = wq_b + (long)l * 3*D_MODEL * D_MODEL;
    const unsigned short* wo_l = wo_b + (long)l * D_MODEL * D_MODEL;
    const unsigned short* w1_l = w1_b + (long)l * D_FF * D_MODEL;
    const unsigned short* w2_l = w2_b + (long)l * D_MODEL * D_FF;
    const float* bqkv_l = bqkv + (long)l * 3*D_MODEL;
    const float* bo_l   = bo   + (long)l * D_MODEL;
    const float* b1_l   = b1   + (long)l * D_FF;
    const float* b2_l   = b2   + (long)l * D_MODEL;

    // qkv = h*Wqkv^T + bqkv  -> bf16 q/kh/vt layouts
    gemm_mfma<MODE_QKV><<<dim3(3*D_MODEL/128, NTOK/128), blk, 0, stream>>>(
        h_b, wq_l, bqkv_l, nullptr, nullptr, nullptr, q_b, kh_b, vth_b,
        D_MODEL, 3*D_MODEL);

    // attention -> ctx_b (bf16)
    attn_mfma<<<dim3(SMAX/64, NHEAD, BATCH), blk, 0, stream>>>(
        q_b, kh_b, vth_b, lens, ctx_b);

    // tmp = h + ctx*Wo^T + bo
    gemm_mfma<MODE_RESID><<<dim3(D_MODEL/128, NTOK/128), blk, 0, stream>>>(
        ctx_b, wo_l, bo_l, h, tmp, nullptr, nullptr, nullptr, nullptr,
        D_MODEL, D_MODEL);

    // h = LN(tmp; ln1) (+ bf16 copy)
    ln_kernel<<<dim3(NTOK), dim3(128), 0, stream>>>(
        tmp, ln1g + l*D_MODEL, ln1b + l*D_MODEL, h, h_b);

    // ff_b = bf16(relu(h*W1^T + b1))
    gemm_mfma<MODE_RELU><<<dim3(D_FF/128, NTOK/128), blk, 0, stream>>>(
        h_b, w1_l, b1_l, nullptr, nullptr, ff_b, nullptr, nullptr, nullptr,
        D_MODEL, D_FF);

    // tmp = h + ff*W2^T + b2
    gemm_mfma<MODE_RESID><<<dim3(D_MODEL/128, NTOK/128), blk, 0, stream>>>(
        ff_b, w2_l, b2_l, h, tmp, nullptr, nullptr, nullptr, nullptr,
        D_FF, D_MODEL);

    // h = LN(tmp; ln2) (+ bf16 copy)
    ln_kernel<<<dim3(NTOK), dim3(128), 0, stream>>>(
        tmp, ln2g + l*D_MODEL, ln2b + l*D_MODEL, h, h_b);
  }

  // 3) masked mean pool + lens output
  out_init<<<dim3((8192 + 16 + 255) / 256), blk, 0, stream>>>(out, lens);
  pool_kernel<<<dim3(SMAX/64, BATCH), blk, 0, stream>>>(h, lens, out);
}

// Round 4
// 814.875 us; speedup vs baseline: 4.9058x; 1.0604x over previous
//
#include <hip/hip_runtime.h>
#include <math.h>

// Problem constants
#define D_MODEL 512
#define NHEAD   8
#define DH      64
#define D_FF    2048
#define BATCH   16
#define SMAX    512
#define NTOK    (BATCH*SMAX)   // 8192
#define NLAYER  4

constexpr int MODE_QKV  = 1;  // scatter bf16 into q/kh/vt layouts, + bias
constexpr int MODE_RELU = 2;  // Cb = bf16(relu(A*B^T + bias))
constexpr int MODE_PART = 3;  // Cb[z] = bf16(A*B^T) partial over K-chunk z

typedef __attribute__((ext_vector_type(8))) __bf16 bf16x8;
typedef __attribute__((ext_vector_type(4))) float  f32x4;

__device__ __forceinline__ unsigned short f2bf(float f) {
  union { float f; unsigned u; } v; v.f = f;
  unsigned r = v.u + 0x7FFFu + ((v.u >> 16) & 1u);   // RNE
  return (unsigned short)(r >> 16);
}
__device__ __forceinline__ float bf2f(unsigned short u) {
  union { unsigned u; float f; } v; v.u = ((unsigned)u) << 16; return v.f;
}

__device__ __forceinline__ void gl_lds16(const unsigned short* g, unsigned short* l) {
  __builtin_amdgcn_global_load_lds(
      (const __attribute__((address_space(1))) unsigned int*)g,
      (__attribute__((address_space(3)))       unsigned int*)l, 16, 0, 0);
}

// ---------------------------------------------------------------------------
// bf16 MFMA GEMM, double-buffered K-loop (1 barrier/iter).
// C[M x N] = op(A[M x K_chunk] * B[N x K_chunk]^T [+ bias])
// 128x128 tile, BK=32, 256 threads = 4 waves (2x2), 4x4 16x16x32 frags/wave.
// MODE_PART: blockIdx.z selects K-chunk of length CK; writes bf16 partial.
// ---------------------------------------------------------------------------
template<int MODE>
__global__ __launch_bounds__(256)
void gemm_mfma(const unsigned short* __restrict__ A,
               const unsigned short* __restrict__ Bw,
               const float* __restrict__ bias,
               unsigned short* __restrict__ Cb,
               unsigned short* __restrict__ qd, unsigned short* __restrict__ kd,
               unsigned short* __restrict__ vd, int K, int CK, int N)
{
  __shared__ __attribute__((aligned(16))) unsigned short As[2][128*32];
  __shared__ __attribute__((aligned(16))) unsigned short Bs[2][128*32];
  const int tid  = threadIdx.x;
  const int m0   = blockIdx.y * 128, n0 = blockIdx.x * 128;
  const int lane = tid & 63;
  const int wm   = ((tid >> 6) & 1) * 64;
  const int wn   = (tid >> 7) * 64;
  const int l15  = lane & 15, quad = lane >> 4;
  const int kz   = (MODE == MODE_PART) ? blockIdx.z : 0;

  f32x4 acc[4][4] = {};

  const int sr = tid >> 2;
  const int sk = (tid & 3) * 8;
  const unsigned short* Ag = A  + (long)(m0 + sr) * K + kz*CK + sk;
  const unsigned short* Bg = Bw + (long)(n0 + sr) * K + kz*CK + sk;
  const long rowskip = (long)64 * K;
  const int t8 = tid * 8;

  // prologue: stage k0=0 into buffer 0
  gl_lds16(Ag,           &As[0][t8]);
  gl_lds16(Ag + rowskip, &As[0][2048 + t8]);
  gl_lds16(Bg,           &Bs[0][t8]);
  gl_lds16(Bg + rowskip, &Bs[0][2048 + t8]);

  for (int k0 = 0; k0 < CK; k0 += 32) {
    const int cur = (k0 >> 5) & 1;
    __syncthreads();              // drains vmcnt -> buf[cur] ready; buf[cur^1] free
    if (k0 + 32 < CK) {
      Ag += 32; Bg += 32;
      gl_lds16(Ag,           &As[cur^1][t8]);
      gl_lds16(Ag + rowskip, &As[cur^1][2048 + t8]);
      gl_lds16(Bg,           &Bs[cur^1][t8]);
      gl_lds16(Bg + rowskip, &Bs[cur^1][2048 + t8]);
    }
    bf16x8 af[4], bfv[4];
#pragma unroll
    for (int i = 0; i < 4; i++)
      af[i] = *(const bf16x8*)&As[cur][(wm + i*16 + l15)*32 + quad*8];
#pragma unroll
    for (int j = 0; j < 4; j++)
      bfv[j] = *(const bf16x8*)&Bs[cur][(wn + j*16 + l15)*32 + quad*8];
#pragma unroll
    for (int i = 0; i < 4; i++)
#pragma unroll
      for (int j = 0; j < 4; j++)
        acc[i][j] = __builtin_amdgcn_mfma_f32_16x16x32_bf16(af[i], bfv[j], acc[i][j], 0, 0, 0);
  }

  // epilogue: D[row = quad*4+r][col = l15] per 16x16 tile
#pragma unroll
  for (int i = 0; i < 4; i++) {
    const int mb = m0 + wm + i*16 + quad*4;
#pragma unroll
    for (int j = 0; j < 4; j++) {
      const int nn = n0 + wn + j*16 + l15;
      if (MODE == MODE_QKV) {
        const float bv = bias[nn];
        const int which = nn >> 9;
        const int head  = (nn >> 6) & 7;
        const int col   = nn & 63;
#pragma unroll
        for (int r = 0; r < 4; r++) {
          int m = mb + r; int bb = m >> 9, s = m & 511;
          int bh = bb*8 + head;
          unsigned short o = f2bf(acc[i][j][r] + bv);
          if (which == 0)
            qd[((long)(bh*512 + s))*64 + col] = o;
          else if (which == 1)
            kd[(long)(bh*8 + (s>>6))*4096 + (col>>5)*2048 + (s&63)*32 + (col&31)] = o;
          else
            vd[(long)(bh*8 + (s>>6))*4096 + ((s&63)>>5)*2048 + col*32 + (s&31)] = o;
        }
      } else if (MODE == MODE_RELU) {
        const float bv = bias[nn];
#pragma unroll
        for (int r = 0; r < 4; r++) {
          int m = mb + r;
          Cb[(long)m*N + nn] = f2bf(fmaxf(acc[i][j][r] + bv, 0.f));
        }
      } else {  // MODE_PART: raw partial, bias added in reduce_ln
#pragma unroll
        for (int r = 0; r < 4; r++) {
          int m = mb + r;
          Cb[((long)kz*NTOK + m)*N + nn] = f2bf(acc[i][j][r]);
        }
      }
    }
  }
}

// ---------------------------------------------------------------------------
// Fused split-K reduce + bias + residual + LayerNorm.
// part: [KS][NTOK][512] bf16 partials; h: fp32 residual in, LN result out;
// hb: bf16 copy out. One block (128 thr x 4 elems) per row.
// ---------------------------------------------------------------------------
template<int KS>
__global__ __launch_bounds__(128)
void reduce_ln(const unsigned short* __restrict__ part,
               const float* __restrict__ bias,
               const float* __restrict__ g, const float* __restrict__ bb,
               float* __restrict__ h, unsigned short* __restrict__ hb)
{
  const int row = blockIdx.x, tid = threadIdx.x;
  float4 x  = ((const float4*)(h + (long)row*512))[tid];
  float4 bs = ((const float4*)bias)[tid];
  float v0 = x.x + bs.x, v1 = x.y + bs.y, v2 = x.z + bs.z, v3 = x.w + bs.w;
#pragma unroll
  for (int z = 0; z < KS; z++) {
    ushort4 p = ((const ushort4*)(part + ((long)z*NTOK + row)*512))[tid];
    v0 += bf2f(p.x); v1 += bf2f(p.y); v2 += bf2f(p.z); v3 += bf2f(p.w);
  }
  float s  = v0 + v1 + v2 + v3;
  float s2 = v0*v0 + v1*v1 + v2*v2 + v3*v3;
#pragma unroll
  for (int off = 1; off < 64; off <<= 1) {
    s  += __shfl_xor(s, off);
    s2 += __shfl_xor(s2, off);
  }
  __shared__ float rb[4];
  if ((tid & 63) == 0) { rb[(tid>>6)*2] = s; rb[(tid>>6)*2+1] = s2; }
  __syncthreads();
  s = rb[0] + rb[2]; s2 = rb[1] + rb[3];
  const float mean = s * (1.f/512.f);
  const float var  = fmaxf(s2 * (1.f/512.f) - mean*mean, 0.f);
  const float rstd = rsqrtf(var + 1e-5f);
  const int e = tid*4;
  float4 o;
  o.x = (v0-mean)*rstd*g[e+0] + bb[e+0];
  o.y = (v1-mean)*rstd*g[e+1] + bb[e+1];
  o.z = (v2-mean)*rstd*g[e+2] + bb[e+2];
  o.w = (v3-mean)*rstd*g[e+3] + bb[e+3];
  ((float4*)(h + (long)row*512))[tid] = o;
  ushort4 ob;
  ob.x = f2bf(o.x); ob.y = f2bf(o.y); ob.z = f2bf(o.z); ob.w = f2bf(o.w);
  ((ushort4*)(hb + (long)row*512))[tid] = ob;
}

// ---------------------------------------------------------------------------
// MFMA flash attention, double-buffered K/V staging.
// ---------------------------------------------------------------------------
__global__ __launch_bounds__(256)
void attn_mfma(const unsigned short* __restrict__ qg,
               const unsigned short* __restrict__ kh,
               const unsigned short* __restrict__ vth,
               const int* __restrict__ lens,
               unsigned short* __restrict__ ctxb)
{
  __shared__ __attribute__((aligned(16))) unsigned short Ks[2][64*32];
  __shared__ __attribute__((aligned(16))) unsigned short Vts[2][64*32];
  __shared__ __attribute__((aligned(16))) unsigned short Ps[4*16*72];
  const int qt = blockIdx.x, hh = blockIdx.y, b = blockIdx.z;
  const int bh = b*8 + hh;
  const int tid = threadIdx.x;
  const int w = tid >> 6, lane = tid & 63, l15 = lane & 15, quad = lane >> 4;
  const int len = lens[b];
  const int t8 = tid * 8;

  const unsigned short* qrow = qg + ((long)(bh*512 + qt*64 + w*16 + l15))*64;
  const bf16x8 qf0 = *(const bf16x8*)(qrow + quad*8);
  const bf16x8 qf1 = *(const bf16x8*)(qrow + 32 + quad*8);

  f32x4 O[4] = {};
  float mrow[4] = {-1e30f,-1e30f,-1e30f,-1e30f};
  float lrow[4] = {0.f,0.f,0.f,0.f};
  unsigned short* Pw = &Ps[w*16*72];
  const int ntiles = (len + 63) >> 6;

  // prologue stage tile 0 -> buf 0
  {
    const unsigned short* Kg = kh  + ((long)(bh*8 + 0))*4096 + t8;
    const unsigned short* Vg = vth + ((long)(bh*8 + 0))*4096 + t8;
    gl_lds16(Kg,        &Ks[0][t8]);
    gl_lds16(Kg + 2048, &Ks[0][2048 + t8]);
    gl_lds16(Vg,        &Vts[0][t8]);
    gl_lds16(Vg + 2048, &Vts[0][2048 + t8]);
  }

  for (int kt = 0; kt < ntiles; kt++) {
    const int cur = kt & 1;
    __syncthreads();              // buf[cur] loads complete; buf[cur^1] free
    if (kt + 1 < ntiles) {
      const unsigned short* Kg = kh  + ((long)(bh*8 + kt + 1))*4096 + t8;
      const unsigned short* Vg = vth + ((long)(bh*8 + kt + 1))*4096 + t8;
      gl_lds16(Kg,        &Ks[cur^1][t8]);
      gl_lds16(Kg + 2048, &Ks[cur^1][2048 + t8]);
      gl_lds16(Vg,        &Vts[cur^1][t8]);
      gl_lds16(Vg + 2048, &Vts[cur^1][2048 + t8]);
    }

    // S = Q K^T : per wave 16q x 64k, C-layout (row=q=quad*4+r, col=k=l15)
    f32x4 sc[4];
#pragma unroll
    for (int ks = 0; ks < 4; ks++) {
      bf16x8 kf0 = *(const bf16x8*)&Ks[cur][       (ks*16 + l15)*32 + quad*8];
      bf16x8 kf1 = *(const bf16x8*)&Ks[cur][2048 + (ks*16 + l15)*32 + quad*8];
      f32x4 z = {};
      z = __builtin_amdgcn_mfma_f32_16x16x32_bf16(qf0, kf0, z, 0, 0, 0);
      sc[ks] = __builtin_amdgcn_mfma_f32_16x16x32_bf16(qf1, kf1, z, 0, 0, 0);
    }

#pragma unroll
    for (int ks = 0; ks < 4; ks++) {
      const bool valid = (kt*64 + ks*16 + l15) < len;
#pragma unroll
      for (int r = 0; r < 4; r++)
        sc[ks][r] = valid ? sc[ks][r]*0.125f : -1e30f;
    }

    float pv[4][4];
#pragma unroll
    for (int r = 0; r < 4; r++) {
      float mx = fmaxf(fmaxf(sc[0][r], sc[1][r]), fmaxf(sc[2][r], sc[3][r]));
      mx = fmaxf(mx, __shfl_xor(mx, 1));
      mx = fmaxf(mx, __shfl_xor(mx, 2));
      mx = fmaxf(mx, __shfl_xor(mx, 4));
      mx = fmaxf(mx, __shfl_xor(mx, 8));
      const float newm  = fmaxf(mrow[r], mx);
      const float alpha = __expf(mrow[r] - newm);
      float ps = 0.f;
#pragma unroll
      for (int ks = 0; ks < 4; ks++) { pv[ks][r] = __expf(sc[ks][r] - newm); ps += pv[ks][r]; }
      ps += __shfl_xor(ps, 1); ps += __shfl_xor(ps, 2);
      ps += __shfl_xor(ps, 4); ps += __shfl_xor(ps, 8);
      lrow[r] = lrow[r]*alpha + ps;
      mrow[r] = newm;
#pragma unroll
      for (int d = 0; d < 4; d++) O[d][r] *= alpha;
    }

    // P: C-layout -> A-layout via wave-private LDS
#pragma unroll
    for (int ks = 0; ks < 4; ks++)
#pragma unroll
      for (int r = 0; r < 4; r++)
        Pw[(quad*4 + r)*72 + ks*16 + l15] = f2bf(pv[ks][r]);
    asm volatile("s_waitcnt lgkmcnt(0)" ::: "memory");

    const bf16x8 pa0 = *(const bf16x8*)&Pw[l15*72 + quad*8];
    const bf16x8 pa1 = *(const bf16x8*)&Pw[l15*72 + 32 + quad*8];
#pragma unroll
    for (int d = 0; d < 4; d++) {
      bf16x8 vf0 = *(const bf16x8*)&Vts[cur][       (d*16 + l15)*32 + quad*8];
      bf16x8 vf1 = *(const bf16x8*)&Vts[cur][2048 + (d*16 + l15)*32 + quad*8];
      O[d] = __builtin_amdgcn_mfma_f32_16x16x32_bf16(pa0, vf0, O[d], 0, 0, 0);
      O[d] = __builtin_amdgcn_mfma_f32_16x16x32_bf16(pa1, vf1, O[d], 0, 0, 0);
    }
  }

#pragma unroll
  for (int r = 0; r < 4; r++) {
    const float inv = 1.f / lrow[r];
    const long row = (long)(b*512 + qt*64 + w*16 + quad*4 + r)*512 + hh*64;
#pragma unroll
    for (int d = 0; d < 4; d++)
      ctxb[row + d*16 + l15] = f2bf(O[d][r] * inv);
  }
}

// ---------------------------------------------------------------------------
// fp32 embedding GEMM (K=80): h = x*We^T + be + posenc; writes fp32 + bf16.
// ---------------------------------------------------------------------------
__global__ __launch_bounds__(256)
void gemm_embed(const float* __restrict__ A, const float* __restrict__ Bm,
                const float* __restrict__ bias, float* __restrict__ C,
                unsigned short* __restrict__ Cb, int K, int N)
{
  __shared__ float As[8][132];
  __shared__ float Bs[8][68];
  const int tid = threadIdx.x;
  const int m0 = blockIdx.y * 128;
  const int n0 = blockIdx.x * 64;
  const int tx = tid & 15, ty = tid >> 4;
  const int a_k = tid & 7, a_m = tid >> 3;

  float acc[8][4] = {};
  const float* Ag = A  + (long)(m0 + a_m) * K + a_k;
  const float* Bg = Bm + (long)(n0 + a_m) * K + a_k;

  for (int k0 = 0; k0 < K; k0 += 8) {
#pragma unroll
    for (int i = 0; i < 4; i++)
      As[a_k][a_m + 32*i] = Ag[k0 + (long)32*i*K];
#pragma unroll
    for (int i = 0; i < 2; i++)
      Bs[a_k][a_m + 32*i] = Bg[k0 + (long)32*i*K];
    __syncthreads();
#pragma unroll
    for (int kk = 0; kk < 8; kk++) {
      float a[8], bv[4];
#pragma unroll
      for (int r = 0; r < 8; r++) a[r] = As[kk][ty*8 + r];
#pragma unroll
      for (int c = 0; c < 4; c++) bv[c] = Bs[kk][tx*4 + c];
#pragma unroll
      for (int r = 0; r < 8; r++)
#pragma unroll
        for (int c = 0; c < 4; c++)
          acc[r][c] += a[r] * bv[c];
    }
    __syncthreads();
  }

  const int n_base = n0 + tx*4;
#pragma unroll
  for (int r = 0; r < 8; r++) {
    int m = m0 + ty*8 + r;
    int s = m & 511;
    float4 v4; float* vp = &v4.x;
#pragma unroll
    for (int c = 0; c < 4; c++) {
      int e = n_base + c;
      float dv  = __expf((float)(e & ~1) * (-9.210340371976184f / 512.0f));
      float ang = (float)s * dv;
      vp[c] = acc[r][c] + bias[e] + ((e & 1) ? cosf(ang) : sinf(ang));
    }
    *(float4*)(C + (long)m*N + n_base) = v4;
    ushort4 ob;
    ob.x = f2bf(v4.x); ob.y = f2bf(v4.y); ob.z = f2bf(v4.z); ob.w = f2bf(v4.w);
    *(ushort4*)(Cb + (long)m*N + n_base) = ob;
  }
}

// fp32 -> bf16 cast (weights)
__global__ __launch_bounds__(256)
void cvt_kernel(const float* __restrict__ in, unsigned short* __restrict__ out, int n4)
{
  int i = blockIdx.x*256 + threadIdx.x;
  if (i < n4) {
    float4 v = ((const float4*)in)[i];
    ushort4 o;
    o.x = f2bf(v.x); o.y = f2bf(v.y); o.z = f2bf(v.z); o.w = f2bf(v.w);
    ((ushort4*)out)[i] = o;
  }
}

__global__ __launch_bounds__(256)
void out_init(float* __restrict__ out, const int* __restrict__ lens)
{
  int i = blockIdx.x*256 + threadIdx.x;
  if (i < 8192) out[i] = 0.f;
  else if (i < 8192 + 16) out[i] = (float)lens[i - 8192];
}

__global__ __launch_bounds__(256)
void pool_kernel(const float* __restrict__ h, const int* __restrict__ lens,
                 float* __restrict__ out)
{
  const int b = blockIdx.y;
  const int s0 = blockIdx.x * 64;
  const int len = lens[b];
  if (s0 >= len) return;
  const int send = min(s0 + 64, len);
  const int tid = threadIdx.x;
  float acc0 = 0.f, acc1 = 0.f;
  for (int s = s0; s < send; s++) {
    const float* row = h + (long)(b*512 + s)*512;
    acc0 += row[tid];
    acc1 += row[tid + 256];
  }
  const float inv = 1.0f / (float)len;
  atomicAdd(out + b*512 + tid,       acc0 * inv);
  atomicAdd(out + b*512 + tid + 256, acc1 * inv);
}

// ---------------------------------------------------------------------------
extern "C" void kernel_launch(void* const* d_in, const int* in_sizes, int n_in,
                              void* d_out, int out_size, void* d_ws, size_t ws_size,
                              hipStream_t stream)
{
  const float* x    = (const float*)d_in[0];
  const int*   lens = (const int*)  d_in[1];
  const float* We   = (const float*)d_in[2];
  const float* be   = (const float*)d_in[3];
  const float* Wqkv = (const float*)d_in[4];
  const float* bqkv = (const float*)d_in[5];
  const float* Wo   = (const float*)d_in[6];
  const float* bo   = (const float*)d_in[7];
  const float* ln1g = (const float*)d_in[8];
  const float* ln1b = (const float*)d_in[9];
  const float* W1   = (const float*)d_in[10];
  const float* b1   = (const float*)d_in[11];
  const float* W2   = (const float*)d_in[12];
  const float* b2   = (const float*)d_in[13];
  const float* ln2g = (const float*)d_in[14];
  const float* ln2b = (const float*)d_in[15];
  float* out = (float*)d_out;

  // Workspace layout (~150 MB)
  const long TOK_D = (long)NTOK * D_MODEL;              // 4,194,304
  float* ws  = (float*)d_ws;
  float* h   = ws;                                      // fp32 [8192,512]
  unsigned short* us    = (unsigned short*)(ws + 1*TOK_D);
  unsigned short* h_b   = us;                           // bf16 [8192,512]
  unsigned short* ctx_b = us + 1*TOK_D;
  unsigned short* q_b   = us + 2*TOK_D;                 // [bh][s][64]
  unsigned short* kh_b  = us + 3*TOK_D;                 // [bh][kt][half][64][32]
  unsigned short* vth_b = us + 4*TOK_D;                 // [bh][kt][half][64][32]
  unsigned short* ff_b  = us + 5*TOK_D;                 // bf16 [8192,2048]
  unsigned short* wq_b  = us + 9*TOK_D;
  unsigned short* wo_b  = wq_b + (long)NLAYER*3*D_MODEL*D_MODEL;
  unsigned short* w1_b  = wo_b + (long)NLAYER*D_MODEL*D_MODEL;
  unsigned short* w2_b  = w1_b + (long)NLAYER*D_FF*D_MODEL;
  unsigned short* part  = w2_b + (long)NLAYER*D_MODEL*D_FF;  // [<=4][8192][512]

  const dim3 blk(256);

  // 0) weight casts fp32->bf16
  {
    int n4;
    n4 = NLAYER*3*D_MODEL*D_MODEL/4;
    cvt_kernel<<<dim3((n4+255)/256), blk, 0, stream>>>(Wqkv, wq_b, n4);
    n4 = NLAYER*D_MODEL*D_MODEL/4;
    cvt_kernel<<<dim3((n4+255)/256), blk, 0, stream>>>(Wo, wo_b, n4);
    n4 = NLAYER*D_FF*D_MODEL/4;
    cvt_kernel<<<dim3((n4+255)/256), blk, 0, stream>>>(W1, w1_b, n4);
    n4 = NLAYER*D_MODEL*D_FF/4;
    cvt_kernel<<<dim3((n4+255)/256), blk, 0, stream>>>(W2, w2_b, n4);
  }

  // 1) embedding + posenc (fp32), writes h + h_b
  gemm_embed<<<dim3(D_MODEL/64, NTOK/128), blk, 0, stream>>>(
      x, We, be, h, h_b, 80, D_MODEL);

  for (int l = 0; l < NLAYER; l++) {
    const unsigned short* wq_l = wq_b + (long)l * 3*D_MODEL * D_MODEL;
    const unsigned short* wo_l = wo_b + (long)l * D_MODEL * D_MODEL;
    const unsigned short* w1_l = w1_b + (long)l * D_FF * D_MODEL;
    const unsigned short* w2_l = w2_b + (long)l * D_MODEL * D_FF;
    const float* bqkv_l = bqkv + (long)l * 3*D_MODEL;
    const float* bo_l   = bo   + (long)l * D_MODEL;
    const float* b1_l   = b1   + (long)l * D_FF;
    const float* b2_l   = b2   + (long)l * D_MODEL;

    // qkv = h*Wqkv^T + bqkv  -> bf16 q/kh/vt layouts
    gemm_mfma<MODE_QKV><<<dim3(3*D_MODEL/128, NTOK/128), blk, 0, stream>>>(
        h_b, wq_l, bqkv_l, nullptr, q_b, kh_b, vth_b, D_MODEL, D_MODEL, 3*D_MODEL);

    // attention -> ctx_b (bf16)
    attn_mfma<<<dim3(SMAX/64, NHEAD, BATCH), blk, 0, stream>>>(
        q_b, kh_b, vth_b, lens, ctx_b);

    // Wo partials: split-K x2 (CK=256), then fused reduce+resid+LN1
    gemm_mfma<MODE_PART><<<dim3(D_MODEL/128, NTOK/128, 2), blk, 0, stream>>>(
        ctx_b, wo_l, nullptr, part, nullptr, nullptr, nullptr,
        D_MODEL, D_MODEL/2, D_MODEL);
    reduce_ln<2><<<dim3(NTOK), dim3(128), 0, stream>>>(
        part, bo_l, ln1g + l*D_MODEL, ln1b + l*D_MODEL, h, h_b);

    // ff_b = bf16(relu(h*W1^T + b1))
    gemm_mfma<MODE_RELU><<<dim3(D_FF/128, NTOK/128), blk, 0, stream>>>(
        h_b, w1_l, b1_l, ff_b, nullptr, nullptr, nullptr, D_MODEL, D_MODEL, D_FF);

    // FF2 partials: split-K x4 (CK=512), then fused reduce+resid+LN2
    gemm_mfma<MODE_PART><<<dim3(D_MODEL/128, NTOK/128, 4), blk, 0, stream>>>(
        ff_b, w2_l, nullptr, part, nullptr, nullptr, nullptr,
        D_FF, D_FF/4, D_MODEL);
    reduce_ln<4><<<dim3(NTOK), dim3(128), 0, stream>>>(
        part, b2_l, ln2g + l*D_MODEL, ln2b + l*D_MODEL, h, h_b);
  }

  // 3) masked mean pool + lens output
  out_init<<<dim3((8192 + 16 + 255) / 256), blk, 0, stream>>>(out, lens);
  pool_kernel<<<dim3(SMAX/64, BATCH), blk, 0, stream>>>(h, lens, out);
}

// Round 5
// 811.850 us; speedup vs baseline: 4.9241x; 1.0037x over previous
//
#include <hip/hip_runtime.h>
#include <math.h>

// Problem constants
#define D_MODEL 512
#define NHEAD   8
#define DH      64
#define D_FF    2048
#define BATCH   16
#define SMAX    512
#define NTOK    (BATCH*SMAX)   // 8192
#define NLAYER  4

constexpr int MODE_QKV  = 1;  // scatter bf16 into q/kh/vt layouts, + bias
constexpr int MODE_RELU = 2;  // Cb = bf16(relu(A*B^T + bias))
constexpr int MODE_PART = 3;  // Cb[z] = bf16(A*B^T) partial over K-chunk z

typedef __attribute__((ext_vector_type(8))) __bf16 bf16x8;
typedef __attribute__((ext_vector_type(4))) float  f32x4;

__device__ __forceinline__ unsigned short f2bf(float f) {
  union { float f; unsigned u; } v; v.f = f;
  unsigned r = v.u + 0x7FFFu + ((v.u >> 16) & 1u);   // RNE
  return (unsigned short)(r >> 16);
}
__device__ __forceinline__ float bf2f(unsigned short u) {
  union { unsigned u; float f; } v; v.u = ((unsigned)u) << 16; return v.f;
}

__device__ __forceinline__ void gl_lds16(const unsigned short* g, unsigned short* l) {
  __builtin_amdgcn_global_load_lds(
      (const __attribute__((address_space(1))) unsigned int*)g,
      (__attribute__((address_space(3)))       unsigned int*)l, 16, 0, 0);
}

// ---------------------------------------------------------------------------
// bf16 MFMA GEMM, double-buffered K-loop, 128 threads = 2 waves.
// Block tile 128x128, BK=32. Each wave computes 64x128: 4 A-frags x 8 B-frags
// = 12 ds_read_b128 -> 32 MFMAs per iter (2.67 MFMA/read vs 2.0 before).
// 4 blocks/CU resident (LDS 32 KB, VGPR ~205 < 256 cap).
// MODE_PART: blockIdx.z selects K-chunk of length CK; writes bf16 partial.
// ---------------------------------------------------------------------------
template<int MODE>
__global__ __launch_bounds__(128, 2)
void gemm_mfma(const unsigned short* __restrict__ A,
               const unsigned short* __restrict__ Bw,
               const float* __restrict__ bias,
               unsigned short* __restrict__ Cb,
               unsigned short* __restrict__ qd, unsigned short* __restrict__ kd,
               unsigned short* __restrict__ vd, int K, int CK, int N)
{
  __shared__ __attribute__((aligned(16))) unsigned short As[2][128*32];
  __shared__ __attribute__((aligned(16))) unsigned short Bs[2][128*32];
  const int tid  = threadIdx.x;
  const int m0   = blockIdx.y * 128, n0 = blockIdx.x * 128;
  const int lane = tid & 63;
  const int wm   = (tid >> 6) * 64;       // wave m-offset (0 or 64)
  const int l15  = lane & 15, quad = lane >> 4;
  const int kz   = (MODE == MODE_PART) ? blockIdx.z : 0;

  f32x4 acc[4][8] = {};

  // staging: 128 threads x 16B = 2 KB (32 rows) per call; 4 calls per operand
  const int sr = tid >> 2;            // 0..31
  const int sk = (tid & 3) * 8;       // 0,8,16,24
  const unsigned short* Ag = A  + (long)(m0 + sr) * K + kz*CK + sk;
  const unsigned short* Bg = Bw + (long)(n0 + sr) * K + kz*CK + sk;
  const long rowskip = (long)32 * K;  // 32 rows per staging call
  const int t8 = tid * 8;

  // prologue: stage k0=0 into buffer 0
#pragma unroll
  for (int c = 0; c < 4; c++) {
    gl_lds16(Ag + c*rowskip, &As[0][c*1024 + t8]);
    gl_lds16(Bg + c*rowskip, &Bs[0][c*1024 + t8]);
  }

  for (int k0 = 0; k0 < CK; k0 += 32) {
    const int cur = (k0 >> 5) & 1;
    __syncthreads();              // buf[cur] ready; buf[cur^1] free
    if (k0 + 32 < CK) {
      Ag += 32; Bg += 32;
#pragma unroll
      for (int c = 0; c < 4; c++) {
        gl_lds16(Ag + c*rowskip, &As[cur^1][c*1024 + t8]);
        gl_lds16(Bg + c*rowskip, &Bs[cur^1][c*1024 + t8]);
      }
    }
    bf16x8 af[4], bfv[8];
#pragma unroll
    for (int i = 0; i < 4; i++)
      af[i] = *(const bf16x8*)&As[cur][(wm + i*16 + l15)*32 + quad*8];
#pragma unroll
    for (int j = 0; j < 8; j++)
      bfv[j] = *(const bf16x8*)&Bs[cur][(j*16 + l15)*32 + quad*8];
#pragma unroll
    for (int i = 0; i < 4; i++)
#pragma unroll
      for (int j = 0; j < 8; j++)
        acc[i][j] = __builtin_amdgcn_mfma_f32_16x16x32_bf16(af[i], bfv[j], acc[i][j], 0, 0, 0);
  }

  // epilogue: D[row = quad*4+r][col = l15] per 16x16 tile
#pragma unroll
  for (int i = 0; i < 4; i++) {
    const int mb = m0 + wm + i*16 + quad*4;
#pragma unroll
    for (int j = 0; j < 8; j++) {
      const int nn = n0 + j*16 + l15;
      if (MODE == MODE_QKV) {
        const float bv = bias[nn];
        const int which = nn >> 9;
        const int head  = (nn >> 6) & 7;
        const int col   = nn & 63;
#pragma unroll
        for (int r = 0; r < 4; r++) {
          int m = mb + r; int bb = m >> 9, s = m & 511;
          int bh = bb*8 + head;
          unsigned short o = f2bf(acc[i][j][r] + bv);
          if (which == 0)
            qd[((long)(bh*512 + s))*64 + col] = o;
          else if (which == 1)
            kd[(long)(bh*8 + (s>>6))*4096 + (col>>5)*2048 + (s&63)*32 + (col&31)] = o;
          else
            vd[(long)(bh*8 + (s>>6))*4096 + ((s&63)>>5)*2048 + col*32 + (s&31)] = o;
        }
      } else if (MODE == MODE_RELU) {
        const float bv = bias[nn];
#pragma unroll
        for (int r = 0; r < 4; r++) {
          int m = mb + r;
          Cb[(long)m*N + nn] = f2bf(fmaxf(acc[i][j][r] + bv, 0.f));
        }
      } else {  // MODE_PART: raw partial, bias added in reduce_ln
#pragma unroll
        for (int r = 0; r < 4; r++) {
          int m = mb + r;
          Cb[((long)kz*NTOK + m)*N + nn] = f2bf(acc[i][j][r]);
        }
      }
    }
  }
}

// ---------------------------------------------------------------------------
// Fused split-K reduce + bias + residual + LayerNorm.
// ---------------------------------------------------------------------------
template<int KS>
__global__ __launch_bounds__(128)
void reduce_ln(const unsigned short* __restrict__ part,
               const float* __restrict__ bias,
               const float* __restrict__ g, const float* __restrict__ bb,
               float* __restrict__ h, unsigned short* __restrict__ hb)
{
  const int row = blockIdx.x, tid = threadIdx.x;
  float4 x  = ((const float4*)(h + (long)row*512))[tid];
  float4 bs = ((const float4*)bias)[tid];
  float v0 = x.x + bs.x, v1 = x.y + bs.y, v2 = x.z + bs.z, v3 = x.w + bs.w;
#pragma unroll
  for (int z = 0; z < KS; z++) {
    ushort4 p = ((const ushort4*)(part + ((long)z*NTOK + row)*512))[tid];
    v0 += bf2f(p.x); v1 += bf2f(p.y); v2 += bf2f(p.z); v3 += bf2f(p.w);
  }
  float s  = v0 + v1 + v2 + v3;
  float s2 = v0*v0 + v1*v1 + v2*v2 + v3*v3;
#pragma unroll
  for (int off = 1; off < 64; off <<= 1) {
    s  += __shfl_xor(s, off);
    s2 += __shfl_xor(s2, off);
  }
  __shared__ float rb[4];
  if ((tid & 63) == 0) { rb[(tid>>6)*2] = s; rb[(tid>>6)*2+1] = s2; }
  __syncthreads();
  s = rb[0] + rb[2]; s2 = rb[1] + rb[3];
  const float mean = s * (1.f/512.f);
  const float var  = fmaxf(s2 * (1.f/512.f) - mean*mean, 0.f);
  const float rstd = rsqrtf(var + 1e-5f);
  const int e = tid*4;
  float4 o;
  o.x = (v0-mean)*rstd*g[e+0] + bb[e+0];
  o.y = (v1-mean)*rstd*g[e+1] + bb[e+1];
  o.z = (v2-mean)*rstd*g[e+2] + bb[e+2];
  o.w = (v3-mean)*rstd*g[e+3] + bb[e+3];
  ((float4*)(h + (long)row*512))[tid] = o;
  ushort4 ob;
  ob.x = f2bf(o.x); ob.y = f2bf(o.y); ob.z = f2bf(o.z); ob.w = f2bf(o.w);
  ((ushort4*)(hb + (long)row*512))[tid] = ob;
}

// ---------------------------------------------------------------------------
// MFMA flash attention, double-buffered K/V staging.
// ---------------------------------------------------------------------------
__global__ __launch_bounds__(256)
void attn_mfma(const unsigned short* __restrict__ qg,
               const unsigned short* __restrict__ kh,
               const unsigned short* __restrict__ vth,
               const int* __restrict__ lens,
               unsigned short* __restrict__ ctxb)
{
  __shared__ __attribute__((aligned(16))) unsigned short Ks[2][64*32];
  __shared__ __attribute__((aligned(16))) unsigned short Vts[2][64*32];
  __shared__ __attribute__((aligned(16))) unsigned short Ps[4*16*72];
  const int qt = blockIdx.x, hh = blockIdx.y, b = blockIdx.z;
  const int bh = b*8 + hh;
  const int tid = threadIdx.x;
  const int w = tid >> 6, lane = tid & 63, l15 = lane & 15, quad = lane >> 4;
  const int len = lens[b];
  const int t8 = tid * 8;

  const unsigned short* qrow = qg + ((long)(bh*512 + qt*64 + w*16 + l15))*64;
  const bf16x8 qf0 = *(const bf16x8*)(qrow + quad*8);
  const bf16x8 qf1 = *(const bf16x8*)(qrow + 32 + quad*8);

  f32x4 O[4] = {};
  float mrow[4] = {-1e30f,-1e30f,-1e30f,-1e30f};
  float lrow[4] = {0.f,0.f,0.f,0.f};
  unsigned short* Pw = &Ps[w*16*72];
  const int ntiles = (len + 63) >> 6;

  // prologue stage tile 0 -> buf 0
  {
    const unsigned short* Kg = kh  + ((long)(bh*8 + 0))*4096 + t8;
    const unsigned short* Vg = vth + ((long)(bh*8 + 0))*4096 + t8;
    gl_lds16(Kg,        &Ks[0][t8]);
    gl_lds16(Kg + 2048, &Ks[0][2048 + t8]);
    gl_lds16(Vg,        &Vts[0][t8]);
    gl_lds16(Vg + 2048, &Vts[0][2048 + t8]);
  }

  for (int kt = 0; kt < ntiles; kt++) {
    const int cur = kt & 1;
    __syncthreads();              // buf[cur] loads complete; buf[cur^1] free
    if (kt + 1 < ntiles) {
      const unsigned short* Kg = kh  + ((long)(bh*8 + kt + 1))*4096 + t8;
      const unsigned short* Vg = vth + ((long)(bh*8 + kt + 1))*4096 + t8;
      gl_lds16(Kg,        &Ks[cur^1][t8]);
      gl_lds16(Kg + 2048, &Ks[cur^1][2048 + t8]);
      gl_lds16(Vg,        &Vts[cur^1][t8]);
      gl_lds16(Vg + 2048, &Vts[cur^1][2048 + t8]);
    }

    // S = Q K^T : per wave 16q x 64k, C-layout (row=q=quad*4+r, col=k=l15)
    f32x4 sc[4];
#pragma unroll
    for (int ks = 0; ks < 4; ks++) {
      bf16x8 kf0 = *(const bf16x8*)&Ks[cur][       (ks*16 + l15)*32 + quad*8];
      bf16x8 kf1 = *(const bf16x8*)&Ks[cur][2048 + (ks*16 + l15)*32 + quad*8];
      f32x4 z = {};
      z = __builtin_amdgcn_mfma_f32_16x16x32_bf16(qf0, kf0, z, 0, 0, 0);
      sc[ks] = __builtin_amdgcn_mfma_f32_16x16x32_bf16(qf1, kf1, z, 0, 0, 0);
    }

#pragma unroll
    for (int ks = 0; ks < 4; ks++) {
      const bool valid = (kt*64 + ks*16 + l15) < len;
#pragma unroll
      for (int r = 0; r < 4; r++)
        sc[ks][r] = valid ? sc[ks][r]*0.125f : -1e30f;
    }

    float pv[4][4];
#pragma unroll
    for (int r = 0; r < 4; r++) {
      float mx = fmaxf(fmaxf(sc[0][r], sc[1][r]), fmaxf(sc[2][r], sc[3][r]));
      mx = fmaxf(mx, __shfl_xor(mx, 1));
      mx = fmaxf(mx, __shfl_xor(mx, 2));
      mx = fmaxf(mx, __shfl_xor(mx, 4));
      mx = fmaxf(mx, __shfl_xor(mx, 8));
      const float newm  = fmaxf(mrow[r], mx);
      const float alpha = __expf(mrow[r] - newm);
      float ps = 0.f;
#pragma unroll
      for (int ks = 0; ks < 4; ks++) { pv[ks][r] = __expf(sc[ks][r] - newm); ps += pv[ks][r]; }
      ps += __shfl_xor(ps, 1); ps += __shfl_xor(ps, 2);
      ps += __shfl_xor(ps, 4); ps += __shfl_xor(ps, 8);
      lrow[r] = lrow[r]*alpha + ps;
      mrow[r] = newm;
#pragma unroll
      for (int d = 0; d < 4; d++) O[d][r] *= alpha;
    }

    // P: C-layout -> A-layout via wave-private LDS
#pragma unroll
    for (int ks = 0; ks < 4; ks++)
#pragma unroll
      for (int r = 0; r < 4; r++)
        Pw[(quad*4 + r)*72 + ks*16 + l15] = f2bf(pv[ks][r]);
    asm volatile("s_waitcnt lgkmcnt(0)" ::: "memory");

    const bf16x8 pa0 = *(const bf16x8*)&Pw[l15*72 + quad*8];
    const bf16x8 pa1 = *(const bf16x8*)&Pw[l15*72 + 32 + quad*8];
#pragma unroll
    for (int d = 0; d < 4; d++) {
      bf16x8 vf0 = *(const bf16x8*)&Vts[cur][       (d*16 + l15)*32 + quad*8];
      bf16x8 vf1 = *(const bf16x8*)&Vts[cur][2048 + (d*16 + l15)*32 + quad*8];
      O[d] = __builtin_amdgcn_mfma_f32_16x16x32_bf16(pa0, vf0, O[d], 0, 0, 0);
      O[d] = __builtin_amdgcn_mfma_f32_16x16x32_bf16(pa1, vf1, O[d], 0, 0, 0);
    }
  }

#pragma unroll
  for (int r = 0; r < 4; r++) {
    const float inv = 1.f / lrow[r];
    const long row = (long)(b*512 + qt*64 + w*16 + quad*4 + r)*512 + hh*64;
#pragma unroll
    for (int d = 0; d < 4; d++)
      ctxb[row + d*16 + l15] = f2bf(O[d][r] * inv);
  }
}

// ---------------------------------------------------------------------------
// fp32 embedding GEMM (K=80): h = x*We^T + be + posenc; writes fp32 + bf16.
// ---------------------------------------------------------------------------
__global__ __launch_bounds__(256)
void gemm_embed(const float* __restrict__ A, const float* __restrict__ Bm,
                const float* __restrict__ bias, float* __restrict__ C,
                unsigned short* __restrict__ Cb, int K, int N)
{
  __shared__ float As[8][132];
  __shared__ float Bs[8][68];
  const int tid = threadIdx.x;
  const int m0 = blockIdx.y * 128;
  const int n0 = blockIdx.x * 64;
  const int tx = tid & 15, ty = tid >> 4;
  const int a_k = tid & 7, a_m = tid >> 3;

  float acc[8][4] = {};
  const float* Ag = A  + (long)(m0 + a_m) * K + a_k;
  const float* Bg = Bm + (long)(n0 + a_m) * K + a_k;

  for (int k0 = 0; k0 < K; k0 += 8) {
#pragma unroll
    for (int i = 0; i < 4; i++)
      As[a_k][a_m + 32*i] = Ag[k0 + (long)32*i*K];
#pragma unroll
    for (int i = 0; i < 2; i++)
      Bs[a_k][a_m + 32*i] = Bg[k0 + (long)32*i*K];
    __syncthreads();
#pragma unroll
    for (int kk = 0; kk < 8; kk++) {
      float a[8], bv[4];
#pragma unroll
      for (int r = 0; r < 8; r++) a[r] = As[kk][ty*8 + r];
#pragma unroll
      for (int c = 0; c < 4; c++) bv[c] = Bs[kk][tx*4 + c];
#pragma unroll
      for (int r = 0; r < 8; r++)
#pragma unroll
        for (int c = 0; c < 4; c++)
          acc[r][c] += a[r] * bv[c];
    }
    __syncthreads();
  }

  const int n_base = n0 + tx*4;
#pragma unroll
  for (int r = 0; r < 8; r++) {
    int m = m0 + ty*8 + r;
    int s = m & 511;
    float4 v4; float* vp = &v4.x;
#pragma unroll
    for (int c = 0; c < 4; c++) {
      int e = n_base + c;
      float dv  = __expf((float)(e & ~1) * (-9.210340371976184f / 512.0f));
      float ang = (float)s * dv;
      vp[c] = acc[r][c] + bias[e] + ((e & 1) ? cosf(ang) : sinf(ang));
    }
    *(float4*)(C + (long)m*N + n_base) = v4;
    ushort4 ob;
    ob.x = f2bf(v4.x); ob.y = f2bf(v4.y); ob.z = f2bf(v4.z); ob.w = f2bf(v4.w);
    *(ushort4*)(Cb + (long)m*N + n_base) = ob;
  }
}

// fp32 -> bf16 cast (weights)
__global__ __launch_bounds__(256)
void cvt_kernel(const float* __restrict__ in, unsigned short* __restrict__ out, int n4)
{
  int i = blockIdx.x*256 + threadIdx.x;
  if (i < n4) {
    float4 v = ((const float4*)in)[i];
    ushort4 o;
    o.x = f2bf(v.x); o.y = f2bf(v.y); o.z = f2bf(v.z); o.w = f2bf(v.w);
    ((ushort4*)out)[i] = o;
  }
}

__global__ __launch_bounds__(256)
void out_init(float* __restrict__ out, const int* __restrict__ lens)
{
  int i = blockIdx.x*256 + threadIdx.x;
  if (i < 8192) out[i] = 0.f;
  else if (i < 8192 + 16) out[i] = (float)lens[i - 8192];
}

__global__ __launch_bounds__(256)
void pool_kernel(const float* __restrict__ h, const int* __restrict__ lens,
                 float* __restrict__ out)
{
  const int b = blockIdx.y;
  const int s0 = blockIdx.x * 64;
  const int len = lens[b];
  if (s0 >= len) return;
  const int send = min(s0 + 64, len);
  const int tid = threadIdx.x;
  float acc0 = 0.f, acc1 = 0.f;
  for (int s = s0; s < send; s++) {
    const float* row = h + (long)(b*512 + s)*512;
    acc0 += row[tid];
    acc1 += row[tid + 256];
  }
  const float inv = 1.0f / (float)len;
  atomicAdd(out + b*512 + tid,       acc0 * inv);
  atomicAdd(out + b*512 + tid + 256, acc1 * inv);
}

// ---------------------------------------------------------------------------
extern "C" void kernel_launch(void* const* d_in, const int* in_sizes, int n_in,
                              void* d_out, int out_size, void* d_ws, size_t ws_size,
                              hipStream_t stream)
{
  const float* x    = (const float*)d_in[0];
  const int*   lens = (const int*)  d_in[1];
  const float* We   = (const float*)d_in[2];
  const float* be   = (const float*)d_in[3];
  const float* Wqkv = (const float*)d_in[4];
  const float* bqkv = (const float*)d_in[5];
  const float* Wo   = (const float*)d_in[6];
  const float* bo   = (const float*)d_in[7];
  const float* ln1g = (const float*)d_in[8];
  const float* ln1b = (const float*)d_in[9];
  const float* W1   = (const float*)d_in[10];
  const float* b1   = (const float*)d_in[11];
  const float* W2   = (const float*)d_in[12];
  const float* b2   = (const float*)d_in[13];
  const float* ln2g = (const float*)d_in[14];
  const float* ln2b = (const float*)d_in[15];
  float* out = (float*)d_out;

  // Workspace layout (~150 MB)
  const long TOK_D = (long)NTOK * D_MODEL;              // 4,194,304
  float* ws  = (float*)d_ws;
  float* h   = ws;                                      // fp32 [8192,512]
  unsigned short* us    = (unsigned short*)(ws + 1*TOK_D);
  unsigned short* h_b   = us;                           // bf16 [8192,512]
  unsigned short* ctx_b = us + 1*TOK_D;
  unsigned short* q_b   = us + 2*TOK_D;                 // [bh][s][64]
  unsigned short* kh_b  = us + 3*TOK_D;                 // [bh][kt][half][64][32]
  unsigned short* vth_b = us + 4*TOK_D;                 // [bh][kt][half][64][32]
  unsigned short* ff_b  = us + 5*TOK_D;                 // bf16 [8192,2048]
  unsigned short* wq_b  = us + 9*TOK_D;
  unsigned short* wo_b  = wq_b + (long)NLAYER*3*D_MODEL*D_MODEL;
  unsigned short* w1_b  = wo_b + (long)NLAYER*D_MODEL*D_MODEL;
  unsigned short* w2_b  = w1_b + (long)NLAYER*D_FF*D_MODEL;
  unsigned short* part  = w2_b + (long)NLAYER*D_MODEL*D_FF;  // [<=4][8192][512]

  const dim3 blk(256);
  const dim3 blk128(128);

  // 0) weight casts fp32->bf16
  {
    int n4;
    n4 = NLAYER*3*D_MODEL*D_MODEL/4;
    cvt_kernel<<<dim3((n4+255)/256), blk, 0, stream>>>(Wqkv, wq_b, n4);
    n4 = NLAYER*D_MODEL*D_MODEL/4;
    cvt_kernel<<<dim3((n4+255)/256), blk, 0, stream>>>(Wo, wo_b, n4);
    n4 = NLAYER*D_FF*D_MODEL/4;
    cvt_kernel<<<dim3((n4+255)/256), blk, 0, stream>>>(W1, w1_b, n4);
    n4 = NLAYER*D_MODEL*D_FF/4;
    cvt_kernel<<<dim3((n4+255)/256), blk, 0, stream>>>(W2, w2_b, n4);
  }

  // 1) embedding + posenc (fp32), writes h + h_b
  gemm_embed<<<dim3(D_MODEL/64, NTOK/128), blk, 0, stream>>>(
      x, We, be, h, h_b, 80, D_MODEL);

  for (int l = 0; l < NLAYER; l++) {
    const unsigned short* wq_l = wq_b + (long)l * 3*D_MODEL * D_MODEL;
    const unsigned short* wo_l = wo_b + (long)l * D_MODEL * D_MODEL;
    const unsigned short* w1_l = w1_b + (long)l * D_FF * D_MODEL;
    const unsigned short* w2_l = w2_b + (long)l * D_MODEL * D_FF;
    const float* bqkv_l = bqkv + (long)l * 3*D_MODEL;
    const float* bo_l   = bo   + (long)l * D_MODEL;
    const float* b1_l   = b1   + (long)l * D_FF;
    const float* b2_l   = b2   + (long)l * D_MODEL;

    // qkv = h*Wqkv^T + bqkv  -> bf16 q/kh/vt layouts  (768 blocks)
    gemm_mfma<MODE_QKV><<<dim3(3*D_MODEL/128, NTOK/128), blk128, 0, stream>>>(
        h_b, wq_l, bqkv_l, nullptr, q_b, kh_b, vth_b, D_MODEL, D_MODEL, 3*D_MODEL);

    // attention -> ctx_b (bf16)  (1024 blocks)
    attn_mfma<<<dim3(SMAX/64, NHEAD, BATCH), blk, 0, stream>>>(
        q_b, kh_b, vth_b, lens, ctx_b);

    // Wo partials: split-K x2 (CK=256), then fused reduce+resid+LN1 (512 blocks)
    gemm_mfma<MODE_PART><<<dim3(D_MODEL/128, NTOK/128, 2), blk128, 0, stream>>>(
        ctx_b, wo_l, nullptr, part, nullptr, nullptr, nullptr,
        D_MODEL, D_MODEL/2, D_MODEL);
    reduce_ln<2><<<dim3(NTOK), dim3(128), 0, stream>>>(
        part, bo_l, ln1g + l*D_MODEL, ln1b + l*D_MODEL, h, h_b);

    // ff_b = bf16(relu(h*W1^T + b1))  (1024 blocks)
    gemm_mfma<MODE_RELU><<<dim3(D_FF/128, NTOK/128), blk128, 0, stream>>>(
        h_b, w1_l, b1_l, ff_b, nullptr, nullptr, nullptr, D_MODEL, D_MODEL, D_FF);

    // FF2 partials: split-K x4 (CK=512), then fused reduce+resid+LN2 (1024 blocks)
    gemm_mfma<MODE_PART><<<dim3(D_MODEL/128, NTOK/128, 4), blk128, 0, stream>>>(
        ff_b, w2_l, nullptr, part, nullptr, nullptr, nullptr,
        D_FF, D_FF/4, D_MODEL);
    reduce_ln<4><<<dim3(NTOK), dim3(128), 0, stream>>>(
        part, b2_l, ln2g + l*D_MODEL, ln2b + l*D_MODEL, h, h_b);
  }

  // 3) masked mean pool + lens output
  out_init<<<dim3((8192 + 16 + 255) / 256), blk, 0, stream>>>(out, lens);
  pool_kernel<<<dim3(SMAX/64, BATCH), blk, 0, stream>>>(h, lens, out);
}